// Round 1
// baseline (17938.513 us; speedup 1.0000x reference)
//
#include <hip/hip_runtime.h>
#include <hip/hip_bf16.h>
#include <math.h>

#define D 512
#define NHEAD 16
#define DK 32
#define NLAYER 16
#define FF 1024
#define VOC 32768
#define TTF 384
#define NCORE 256
#define NB 16

// ---------------- embedding gather: out[b, out_off+t, :] = sem[ids[b, id_off+t]] + pos[t] ----------------
__global__ __launch_bounds__(128) void embed_k(
    const int* __restrict__ ids, int id_stride, int id_off,
    const float* __restrict__ sem, const float* __restrict__ pos,
    float* __restrict__ out, int out_stride, int out_off)
{
    int t = blockIdx.x, b = blockIdx.y, tid = threadIdx.x;
    int id = ids[b * id_stride + id_off + t];
    const float4* s4 = reinterpret_cast<const float4*>(sem + (size_t)id * D);
    const float4* p4 = reinterpret_cast<const float4*>(pos + (size_t)t * D);
    float4* o4 = reinterpret_cast<float4*>(out + (size_t)(b * out_stride + out_off + t) * D);
    float4 a = s4[tid], p = p4[tid];
    o4[tid] = make_float4(a.x + p.x, a.y + p.y, a.z + p.z, a.w + p.w);
}

// ---------------- generic fp32 GEMM: C(M,N) = A(M,K) @ W(N,K)^T + bias ----------------
// flags: bit0 = residual add into C, bit1 = exact GELU
__device__ __forceinline__ float gelu_f(float v) {
    return 0.5f * v * (1.0f + erff(v * 0.70710678118654752f));
}

__global__ __launch_bounds__(256) void gemm_k(
    const float* __restrict__ A, const float* __restrict__ W,
    const float* __restrict__ bias, float* __restrict__ C,
    int M, int N, int K, int flags)
{
    __shared__ float As[16][68];   // +4 pad keeps 16B alignment for b128 reads
    __shared__ float Ws[16][68];
    int tid = threadIdx.x;
    int row0 = blockIdx.y * 64;
    int col0 = blockIdx.x * 64;
    int lr = tid >> 2;            // 0..63 : tile row loaded by this thread
    int lk = (tid & 3) * 4;       // 0,4,8,12 : k-offset (float4)
    int tx = tid & 15, ty = tid >> 4;
    float acc[4][4] = {};
    const float* Ap = A + (size_t)(row0 + lr) * K + lk;
    const float* Wp = W + (size_t)(col0 + lr) * K + lk;
    for (int k0 = 0; k0 < K; k0 += 16) {
        float4 a4 = *reinterpret_cast<const float4*>(Ap + k0);
        float4 w4 = *reinterpret_cast<const float4*>(Wp + k0);
        As[lk + 0][lr] = a4.x; As[lk + 1][lr] = a4.y; As[lk + 2][lr] = a4.z; As[lk + 3][lr] = a4.w;
        Ws[lk + 0][lr] = w4.x; Ws[lk + 1][lr] = w4.y; Ws[lk + 2][lr] = w4.z; Ws[lk + 3][lr] = w4.w;
        __syncthreads();
        #pragma unroll
        for (int kk = 0; kk < 16; kk++) {
            float4 av = *reinterpret_cast<const float4*>(&As[kk][ty * 4]);
            float4 wv = *reinterpret_cast<const float4*>(&Ws[kk][tx * 4]);
            float avv[4] = {av.x, av.y, av.z, av.w};
            float wvv[4] = {wv.x, wv.y, wv.z, wv.w};
            #pragma unroll
            for (int i = 0; i < 4; i++)
                #pragma unroll
                for (int j = 0; j < 4; j++)
                    acc[i][j] += avv[i] * wvv[j];
        }
        __syncthreads();
    }
    #pragma unroll
    for (int i = 0; i < 4; i++) {
        int r = row0 + ty * 4 + i;
        #pragma unroll
        for (int j = 0; j < 4; j++) {
            int c = col0 + tx * 4 + j;
            float v = acc[i][j] + bias[c];
            if (flags & 2) v = gelu_f(v);
            size_t off = (size_t)r * N + c;
            if (flags & 1) C[off] += v; else C[off] = v;
        }
    }
}

// ---------------- layernorm with flexible row mapping ----------------
// logical row r: b = r / rpb, t = r % rpb
// in row  = b*in_stride  + in_off  + t ; out row = b*out_stride + out_off + t
__global__ __launch_bounds__(64) void ln_k(
    const float* __restrict__ in, float* __restrict__ out,
    const float* __restrict__ g, const float* __restrict__ bt,
    int rpb, int in_stride, int in_off, int out_stride, int out_off)
{
    int r = blockIdx.x;
    int b = r / rpb, t = r % rpb;
    const float* xr = in + (size_t)(b * in_stride + in_off + t) * D;
    float* yr = out + (size_t)(b * out_stride + out_off + t) * D;
    int lane = threadIdx.x;
    float v[8];
    float s = 0.f;
    #pragma unroll
    for (int i = 0; i < 8; i++) { v[i] = xr[lane + i * 64]; s += v[i]; }
    #pragma unroll
    for (int off = 32; off; off >>= 1) s += __shfl_xor(s, off);
    float mu = s * (1.f / 512.f);
    float vs = 0.f;
    #pragma unroll
    for (int i = 0; i < 8; i++) { float d = v[i] - mu; vs += d * d; }
    #pragma unroll
    for (int off = 32; off; off >>= 1) vs += __shfl_xor(vs, off);
    float rstd = rsqrtf(vs * (1.f / 512.f) + 1e-5f);
    #pragma unroll
    for (int i = 0; i < 8; i++) {
        int c = lane + i * 64;
        yr[c] = (v[i] - mu) * rstd * g[c] + bt[c];
    }
}

// ---------------- summarizer attention: one wave per (b,h,query) ----------------
// q: (64, 512) shared across batch. kv: (B*tlen, 1024) cols [0,512)=k, [512,1024)=v
template<int NI>
__global__ __launch_bounds__(64) void attn_sum_k(
    const float* __restrict__ q, const float* __restrict__ kv,
    float* __restrict__ o, int tlen)
{
    int qi = blockIdx.x, h = blockIdx.y, b = blockIdx.z;
    int lane = threadIdx.x;
    __shared__ float qs[DK];
    if (lane < DK) qs[lane] = q[(size_t)qi * D + h * DK + lane];
    __syncthreads();
    float sc[NI];
    float m = -1e30f;
    #pragma unroll
    for (int i = 0; i < NI; i++) {
        sc[i] = 0.f;
        int t = lane + i * 64;
        if (t < tlen) {
            const float* kr = kv + (size_t)(b * tlen + t) * 1024 + h * DK;
            float d = 0.f;
            #pragma unroll
            for (int dk = 0; dk < DK; dk++) d += qs[dk] * kr[dk];
            d *= 0.17677669529663687f;   // 1/sqrt(32)
            sc[i] = d;
            m = fmaxf(m, d);
        }
    }
    #pragma unroll
    for (int off = 32; off; off >>= 1) m = fmaxf(m, __shfl_xor(m, off));
    float sum = 0.f;
    #pragma unroll
    for (int i = 0; i < NI; i++) {
        int t = lane + i * 64;
        if (t < tlen) { sc[i] = expf(sc[i] - m); sum += sc[i]; }
    }
    #pragma unroll
    for (int off = 32; off; off >>= 1) sum += __shfl_xor(sum, off);
    float inv = 1.f / sum;
    float oa[DK];
    #pragma unroll
    for (int dk = 0; dk < DK; dk++) oa[dk] = 0.f;
    #pragma unroll
    for (int i = 0; i < NI; i++) {
        int t = lane + i * 64;
        if (t < tlen) {
            const float* vr = kv + (size_t)(b * tlen + t) * 1024 + 512 + h * DK;
            float a = sc[i] * inv;
            #pragma unroll
            for (int dk = 0; dk < DK; dk++) oa[dk] += a * vr[dk];
        }
    }
    #pragma unroll
    for (int dk = 0; dk < DK; dk++) {
        float vv = oa[dk];
        #pragma unroll
        for (int off = 32; off; off >>= 1) vv += __shfl_xor(vv, off);
        if (lane == 0) o[(size_t)(b * 64 + qi) * D + h * DK + dk] = vv;
    }
}

// ---------------- core causal attention: one wave per (b,h,pos) ----------------
// qkv: (B*384, 1536) cols [0,512)=q, [512,1024)=k, [1024,1536)=v
__global__ __launch_bounds__(64) void attn_core_k(
    const float* __restrict__ qkv, float* __restrict__ o)
{
    int p = blockIdx.x, h = blockIdx.y, b = blockIdx.z;
    int lane = threadIdx.x;
    __shared__ float qs[DK];
    if (lane < DK) qs[lane] = qkv[(size_t)(b * TTF + p) * 1536 + h * DK + lane];
    __syncthreads();
    int nk = p + 1;
    float sc[6];
    float m = -1e30f;
    #pragma unroll
    for (int i = 0; i < 6; i++) {
        sc[i] = 0.f;
        int t = lane + i * 64;
        if (t < nk) {
            const float* kr = qkv + (size_t)(b * TTF + t) * 1536 + 512 + h * DK;
            float d = 0.f;
            #pragma unroll
            for (int dk = 0; dk < DK; dk++) d += qs[dk] * kr[dk];
            d *= 0.17677669529663687f;
            sc[i] = d;
            m = fmaxf(m, d);
        }
    }
    #pragma unroll
    for (int off = 32; off; off >>= 1) m = fmaxf(m, __shfl_xor(m, off));
    float sum = 0.f;
    #pragma unroll
    for (int i = 0; i < 6; i++) {
        int t = lane + i * 64;
        if (t < nk) { sc[i] = expf(sc[i] - m); sum += sc[i]; }
    }
    #pragma unroll
    for (int off = 32; off; off >>= 1) sum += __shfl_xor(sum, off);
    float inv = 1.f / sum;
    float oa[DK];
    #pragma unroll
    for (int dk = 0; dk < DK; dk++) oa[dk] = 0.f;
    #pragma unroll
    for (int i = 0; i < 6; i++) {
        int t = lane + i * 64;
        if (t < nk) {
            const float* vr = qkv + (size_t)(b * TTF + t) * 1536 + 1024 + h * DK;
            float a = sc[i] * inv;
            #pragma unroll
            for (int dk = 0; dk < DK; dk++) oa[dk] += a * vr[dk];
        }
    }
    #pragma unroll
    for (int dk = 0; dk < DK; dk++) {
        float vv = oa[dk];
        #pragma unroll
        for (int off = 32; off; off >>= 1) vv += __shfl_xor(vv, off);
        if (lane == 0) o[(size_t)(b * TTF + p) * D + h * DK + dk] = vv;
    }
}

// ---------------- tgt copy: out[i] = (float)target_ids[b, 768 + c] ----------------
__global__ __launch_bounds__(256) void tgt_k(const int* __restrict__ tids, float* __restrict__ out)
{
    int i = blockIdx.x * 256 + threadIdx.x;   // 0..4095
    int b = i >> 8, c = i & 255;
    out[i] = (float)tids[b * 1024 + 768 + c];
}

extern "C" void kernel_launch(void* const* d_in, const int* in_sizes, int n_in,
                              void* d_out, int out_size, void* d_ws, size_t ws_size,
                              hipStream_t stream) {
    (void)in_sizes; (void)n_in; (void)out_size; (void)ws_size;
    const int*   input_ids  = (const int*)  d_in[0];
    const int*   target_ids = (const int*)  d_in[1];
    const float* emb_sem    = (const float*)d_in[2];
    const float* emb_pos    = (const float*)d_in[3];
    const float* lg_sem     = (const float*)d_in[4];
    const float* lg_pos     = (const float*)d_in[5];
    const float* lg_inw     = (const float*)d_in[6];
    const float* lg_inb     = (const float*)d_in[7];
    const float* lg_outw    = (const float*)d_in[8];
    const float* lg_outb    = (const float*)d_in[9];
    const float* lg_tok     = (const float*)d_in[10];
    const float* lg_lng     = (const float*)d_in[11];
    const float* lg_lnb     = (const float*)d_in[12];
    const float* md_sem     = (const float*)d_in[13];
    const float* md_pos     = (const float*)d_in[14];
    const float* md_inw     = (const float*)d_in[15];
    const float* md_inb     = (const float*)d_in[16];
    const float* md_outw    = (const float*)d_in[17];
    const float* md_outb    = (const float*)d_in[18];
    const float* md_tok     = (const float*)d_in[19];
    const float* md_lng     = (const float*)d_in[20];
    const float* md_lnb     = (const float*)d_in[21];
    const float* qkv_w      = (const float*)d_in[22];
    const float* qkv_b      = (const float*)d_in[23];
    const float* wo_w       = (const float*)d_in[24];
    const float* wo_b       = (const float*)d_in[25];
    const float* ln1_g      = (const float*)d_in[26];
    const float* ln1_b      = (const float*)d_in[27];
    const float* ln2_g      = (const float*)d_in[28];
    const float* ln2_b      = (const float*)d_in[29];
    const float* ff1_w      = (const float*)d_in[30];
    const float* ff1_b      = (const float*)d_in[31];
    const float* ff2_w      = (const float*)d_in[32];
    const float* ff2_b      = (const float*)d_in[33];
    const float* hd_lng     = (const float*)d_in[34];
    const float* hd_lnb     = (const float*)d_in[35];
    const float* hd_w       = (const float*)d_in[36];
    const float* hd_b       = (const float*)d_in[37];

    float* ws   = (float*)d_ws;
    float* x    = ws;                       // 16*384*512      = 3,145,728
    float* h    = x    + 3145728;           // 3,145,728
    float* qkvb = h    + 3145728;           // 9,437,184 (qkv / summarizer KV / ff1 out)
    float* tmp  = qkvb + 9437184;           // 4,194,304 (summ embeds / attn out)
    float* q_s  = tmp  + 4194304;           // 32,768
    float* sumo = q_s  + 32768;             // 524,288
    float* so2  = sumo + 524288;            // 524,288

    // ======== summarizer LG (tlen=512) ========
    embed_k<<<dim3(512, NB), 128, 0, stream>>>(input_ids, 1024, 0, lg_sem, lg_pos, tmp, 512, 0);
    gemm_k<<<dim3(16, 128), 256, 0, stream>>>(tmp, lg_inw + 512 * 512, lg_inb + 512, qkvb, 8192, 1024, 512, 0);
    gemm_k<<<dim3(8, 1), 256, 0, stream>>>(lg_tok, lg_inw, lg_inb, q_s, 64, 512, 512, 0);
    attn_sum_k<8><<<dim3(64, NHEAD, NB), 64, 0, stream>>>(q_s, qkvb, sumo, 512);
    gemm_k<<<dim3(8, 16), 256, 0, stream>>>(sumo, lg_outw, lg_outb, so2, 1024, 512, 512, 0);
    ln_k<<<1024, 64, 0, stream>>>(so2, x, lg_lng, lg_lnb, 64, 64, 0, TTF, 0);

    // ======== summarizer MD (tlen=256) ========
    embed_k<<<dim3(256, NB), 128, 0, stream>>>(input_ids, 1024, 512, md_sem, md_pos, tmp, 256, 0);
    gemm_k<<<dim3(16, 64), 256, 0, stream>>>(tmp, md_inw + 512 * 512, md_inb + 512, qkvb, 4096, 1024, 512, 0);
    gemm_k<<<dim3(8, 1), 256, 0, stream>>>(md_tok, md_inw, md_inb, q_s, 64, 512, 512, 0);
    attn_sum_k<4><<<dim3(64, NHEAD, NB), 64, 0, stream>>>(q_s, qkvb, sumo, 256);
    gemm_k<<<dim3(8, 16), 256, 0, stream>>>(sumo, md_outw, md_outb, so2, 1024, 512, 512, 0);
    ln_k<<<1024, 64, 0, stream>>>(so2, x, md_lng, md_lnb, 64, 64, 0, TTF, 64);

    // ======== core embeddings into x[:, 128:384, :] ========
    embed_k<<<dim3(256, NB), 128, 0, stream>>>(input_ids, 1024, 768, emb_sem, emb_pos, x, TTF, 128);

    // ======== 16 transformer layers ========
    for (int l = 0; l < NLAYER; l++) {
        ln_k<<<6144, 64, 0, stream>>>(x, h, ln1_g + l * D, ln1_b + l * D, TTF, TTF, 0, TTF, 0);
        gemm_k<<<dim3(24, 96), 256, 0, stream>>>(h, qkv_w + (size_t)l * 1536 * 512, qkv_b + l * 1536, qkvb, 6144, 1536, 512, 0);
        attn_core_k<<<dim3(TTF, NHEAD, NB), 64, 0, stream>>>(qkvb, tmp);
        gemm_k<<<dim3(8, 96), 256, 0, stream>>>(tmp, wo_w + (size_t)l * 512 * 512, wo_b + l * D, x, 6144, 512, 512, 1);
        ln_k<<<6144, 64, 0, stream>>>(x, h, ln2_g + l * D, ln2_b + l * D, TTF, TTF, 0, TTF, 0);
        gemm_k<<<dim3(16, 96), 256, 0, stream>>>(h, ff1_w + (size_t)l * 1024 * 512, ff1_b + l * FF, qkvb, 6144, 1024, 512, 2);
        gemm_k<<<dim3(8, 96), 256, 0, stream>>>(qkvb, ff2_w + (size_t)l * 512 * 1024, ff2_b + l * D, x, 6144, 512, 1024, 1);
    }

    // ======== head ========
    ln_k<<<4096, 64, 0, stream>>>(x, h, hd_lng, hd_lnb, NCORE, TTF, 128, NCORE, 0);
    float* logits = (float*)d_out;
    gemm_k<<<dim3(512, 64), 256, 0, stream>>>(h, hd_w, hd_b, logits, 4096, VOC, 512, 0);
    tgt_k<<<16, 256, 0, stream>>>(target_ids, logits + (size_t)NB * NCORE * VOC);
}

// Round 2
// 12650.800 us; speedup vs baseline: 1.4180x; 1.4180x over previous
//
#include <hip/hip_runtime.h>
#include <hip/hip_bf16.h>
#include <math.h>

#define D 512
#define NHEAD 16
#define DK 32
#define NLAYER 16
#define FF 1024
#define VOC 32768
#define TTF 384
#define NCORE 256
#define NB 16

typedef __attribute__((ext_vector_type(8))) short bfrag;   // 8 bf16 (4 VGPRs)
typedef __attribute__((ext_vector_type(4))) float f32x4;

// ---------- async global->LDS, 16B per lane ----------
typedef __attribute__((address_space(3))) void lds_void;
typedef const __attribute__((address_space(1))) void gbl_void;
__device__ __forceinline__ void gload16(const void* g, void* l) {
    __builtin_amdgcn_global_load_lds((gbl_void*)g, (lds_void*)l, 16, 0, 0);
}

__device__ __forceinline__ float gelu_f(float v) {
    return 0.5f * v * (1.0f + erff(v * 0.70710678118654752f));
}

// ---------------- f32 -> bf16 convert (8 elems/thread) ----------------
__global__ __launch_bounds__(256) void cvt_k(const float* __restrict__ in,
                                             __hip_bfloat16* __restrict__ out, int n)
{
    int i = (blockIdx.x * 256 + threadIdx.x) * 8;
    if (i >= n) return;
    float4 a = *reinterpret_cast<const float4*>(in + i);
    float4 b = *reinterpret_cast<const float4*>(in + i + 4);
    __align__(16) __hip_bfloat16 t[8];
    t[0] = __float2bfloat16(a.x); t[1] = __float2bfloat16(a.y);
    t[2] = __float2bfloat16(a.z); t[3] = __float2bfloat16(a.w);
    t[4] = __float2bfloat16(b.x); t[5] = __float2bfloat16(b.y);
    t[6] = __float2bfloat16(b.z); t[7] = __float2bfloat16(b.w);
    *reinterpret_cast<uint4*>(out + i) = *reinterpret_cast<const uint4*>(t);
}

// ---------------- embedding gather ----------------
// out[b, out_off+t, :] = sem[ids[b, id_off+t]] + pos[t];  OB: 0 = f32 out, 1 = bf16 out
template<int OB>
__global__ __launch_bounds__(128) void embed_k(
    const int* __restrict__ ids, int id_stride, int id_off,
    const float* __restrict__ sem, const float* __restrict__ pos,
    void* __restrict__ out, int out_stride, int out_off)
{
    int t = blockIdx.x, b = blockIdx.y, tid = threadIdx.x;
    int id = ids[b * id_stride + id_off + t];
    const float4* s4 = reinterpret_cast<const float4*>(sem + (size_t)id * D);
    const float4* p4 = reinterpret_cast<const float4*>(pos + (size_t)t * D);
    size_t row = (size_t)(b * out_stride + out_off + t) * D;
    float4 a = s4[tid], p = p4[tid];
    float v0 = a.x + p.x, v1 = a.y + p.y, v2 = a.z + p.z, v3 = a.w + p.w;
    if (OB) {
        __hip_bfloat16* o = (__hip_bfloat16*)out + row + tid * 4;
        o[0] = __float2bfloat16(v0); o[1] = __float2bfloat16(v1);
        o[2] = __float2bfloat16(v2); o[3] = __float2bfloat16(v3);
    } else {
        float4* o4 = reinterpret_cast<float4*>((float*)out + row);
        o4[tid] = make_float4(v0, v1, v2, v3);
    }
}

// ---------------- bf16 MFMA GEMM: C(M,N) = A(M,K) @ W(N,K)^T + bias ----------------
// m97 structure: 128x128 tile, 4 waves (2x2 of 64x64), BK=64, single-buffered LDS,
// staged via global_load_lds width=16. Requires M%128==0, N%128==0, K%64==0.
// flags: 0 = f32 out, 1 = f32 out += (residual), 2 = bf16 out with exact GELU
__global__ __launch_bounds__(256) void mgemm_k(
    const __hip_bfloat16* __restrict__ A, const __hip_bfloat16* __restrict__ W,
    const float* __restrict__ bias, void* __restrict__ C,
    int M, int N, int K, int flags)
{
    __shared__ __align__(16) __hip_bfloat16 sA[128][64];
    __shared__ __align__(16) __hip_bfloat16 sB[128][64];
    int tid = threadIdx.x;
    int w = tid >> 6, lane = tid & 63;
    int wr = w >> 1, wc = w & 1;               // wave's 64x64 quadrant
    int row0 = blockIdx.y * 128, col0 = blockIdx.x * 128;

    // staging source pointers: chunk r covers tile rows r*32+w*8 + lane/8, col (lane&7)*8
    const __hip_bfloat16* gA[4];
    const __hip_bfloat16* gB[4];
    #pragma unroll
    for (int r = 0; r < 4; r++) {
        int trow = r * 32 + w * 8 + (lane >> 3);
        int tcol = (lane & 7) * 8;
        gA[r] = A + (size_t)(row0 + trow) * K + tcol;
        gB[r] = W + (size_t)(col0 + trow) * K + tcol;
    }
    __hip_bfloat16* sAf = &sA[0][0];
    __hip_bfloat16* sBf = &sB[0][0];

    f32x4 acc[4][4];
    #pragma unroll
    for (int m = 0; m < 4; m++)
        #pragma unroll
        for (int n = 0; n < 4; n++) acc[m][n] = (f32x4){0.f, 0.f, 0.f, 0.f};

    int cr = lane >> 4;        // 0..3
    int cc = lane & 15;        // 0..15

    for (int k0 = 0; k0 < K; k0 += 64) {
        #pragma unroll
        for (int r = 0; r < 4; r++) {
            gload16(gA[r] + k0, sAf + r * 2048 + w * 512);
            gload16(gB[r] + k0, sBf + r * 2048 + w * 512);
        }
        __syncthreads();       // drains vmcnt(0): LDS tiles ready
        #pragma unroll
        for (int ks = 0; ks < 2; ks++) {
            int colk = ks * 32 + cr * 8;
            bfrag af[4], bf[4];
            #pragma unroll
            for (int m = 0; m < 4; m++)
                af[m] = *reinterpret_cast<const bfrag*>(&sA[wr * 64 + m * 16 + cc][colk]);
            #pragma unroll
            for (int n = 0; n < 4; n++)
                bf[n] = *reinterpret_cast<const bfrag*>(&sB[wc * 64 + n * 16 + cc][colk]);
            #pragma unroll
            for (int m = 0; m < 4; m++)
                #pragma unroll
                for (int n = 0; n < 4; n++)
                    acc[m][n] = __builtin_amdgcn_mfma_f32_16x16x32_bf16(af[m], bf[n], acc[m][n], 0, 0, 0);
        }
        __syncthreads();       // LDS consumed: safe to overwrite next iter
    }

    // epilogue. C/D layout: col = lane&15, row = (lane>>4)*4 + j
    #pragma unroll
    for (int m = 0; m < 4; m++) {
        int rg = row0 + wr * 64 + m * 16 + cr * 4;
        #pragma unroll
        for (int n = 0; n < 4; n++) {
            int cg = col0 + wc * 64 + n * 16 + cc;
            float bs = bias[cg];
            #pragma unroll
            for (int j = 0; j < 4; j++) {
                float v = acc[m][n][j] + bs;
                size_t off = (size_t)(rg + j) * N + cg;
                if (flags == 1)      ((float*)C)[off] += v;
                else if (flags == 2) ((__hip_bfloat16*)C)[off] = __float2bfloat16(gelu_f(v));
                else                 ((float*)C)[off] = v;
            }
        }
    }
}

// ---------------- small fp32 GEMM (kept for the 64-row query projections) ----------------
__global__ __launch_bounds__(256) void gemm_k(
    const float* __restrict__ A, const float* __restrict__ W,
    const float* __restrict__ bias, float* __restrict__ C,
    int M, int N, int K)
{
    __shared__ float As[16][68];
    __shared__ float Ws[16][68];
    int tid = threadIdx.x;
    int row0 = blockIdx.y * 64;
    int col0 = blockIdx.x * 64;
    int lr = tid >> 2;
    int lk = (tid & 3) * 4;
    int tx = tid & 15, ty = tid >> 4;
    float acc[4][4] = {};
    const float* Ap = A + (size_t)(row0 + lr) * K + lk;
    const float* Wp = W + (size_t)(col0 + lr) * K + lk;
    for (int k0 = 0; k0 < K; k0 += 16) {
        float4 a4 = *reinterpret_cast<const float4*>(Ap + k0);
        float4 w4 = *reinterpret_cast<const float4*>(Wp + k0);
        As[lk + 0][lr] = a4.x; As[lk + 1][lr] = a4.y; As[lk + 2][lr] = a4.z; As[lk + 3][lr] = a4.w;
        Ws[lk + 0][lr] = w4.x; Ws[lk + 1][lr] = w4.y; Ws[lk + 2][lr] = w4.z; Ws[lk + 3][lr] = w4.w;
        __syncthreads();
        #pragma unroll
        for (int kk = 0; kk < 16; kk++) {
            float4 av = *reinterpret_cast<const float4*>(&As[kk][ty * 4]);
            float4 wv = *reinterpret_cast<const float4*>(&Ws[kk][tx * 4]);
            float avv[4] = {av.x, av.y, av.z, av.w};
            float wvv[4] = {wv.x, wv.y, wv.z, wv.w};
            #pragma unroll
            for (int i = 0; i < 4; i++)
                #pragma unroll
                for (int j = 0; j < 4; j++)
                    acc[i][j] += avv[i] * wvv[j];
        }
        __syncthreads();
    }
    #pragma unroll
    for (int i = 0; i < 4; i++) {
        int r = row0 + ty * 4 + i;
        #pragma unroll
        for (int j = 0; j < 4; j++) {
            int c = col0 + tx * 4 + j;
            C[(size_t)r * N + c] = acc[i][j] + bias[c];
        }
    }
}

// ---------------- layernorm, flexible row mapping; OB: 0 = f32 out, 1 = bf16 out ----------------
template<int OB>
__global__ __launch_bounds__(64) void ln_k(
    const float* __restrict__ in, void* __restrict__ out,
    const float* __restrict__ g, const float* __restrict__ bt,
    int rpb, int in_stride, int in_off, int out_stride, int out_off)
{
    int r = blockIdx.x;
    int b = r / rpb, t = r % rpb;
    const float* xr = in + (size_t)(b * in_stride + in_off + t) * D;
    size_t orow = (size_t)(b * out_stride + out_off + t) * D;
    int lane = threadIdx.x;
    float v[8];
    float s = 0.f;
    #pragma unroll
    for (int i = 0; i < 8; i++) { v[i] = xr[lane + i * 64]; s += v[i]; }
    #pragma unroll
    for (int off = 32; off; off >>= 1) s += __shfl_xor(s, off);
    float mu = s * (1.f / 512.f);
    float vs = 0.f;
    #pragma unroll
    for (int i = 0; i < 8; i++) { float d = v[i] - mu; vs += d * d; }
    #pragma unroll
    for (int off = 32; off; off >>= 1) vs += __shfl_xor(vs, off);
    float rstd = rsqrtf(vs * (1.f / 512.f) + 1e-5f);
    #pragma unroll
    for (int i = 0; i < 8; i++) {
        int c = lane + i * 64;
        float y = (v[i] - mu) * rstd * g[c] + bt[c];
        if (OB) ((__hip_bfloat16*)out)[orow + c] = __float2bfloat16(y);
        else    ((float*)out)[orow + c] = y;
    }
}

// ---------------- summarizer attention: one wave per (b,h,query); bf16 out ----------------
template<int NI>
__global__ __launch_bounds__(64) void attn_sum_k(
    const float* __restrict__ q, const float* __restrict__ kv,
    __hip_bfloat16* __restrict__ o, int tlen)
{
    int qi = blockIdx.x, h = blockIdx.y, b = blockIdx.z;
    int lane = threadIdx.x;
    __shared__ float qs[DK];
    if (lane < DK) qs[lane] = q[(size_t)qi * D + h * DK + lane];
    __syncthreads();
    float sc[NI];
    float m = -1e30f;
    #pragma unroll
    for (int i = 0; i < NI; i++) {
        sc[i] = 0.f;
        int t = lane + i * 64;
        if (t < tlen) {
            const float* kr = kv + (size_t)(b * tlen + t) * 1024 + h * DK;
            float d = 0.f;
            #pragma unroll
            for (int dk = 0; dk < DK; dk++) d += qs[dk] * kr[dk];
            d *= 0.17677669529663687f;
            sc[i] = d;
            m = fmaxf(m, d);
        }
    }
    #pragma unroll
    for (int off = 32; off; off >>= 1) m = fmaxf(m, __shfl_xor(m, off));
    float sum = 0.f;
    #pragma unroll
    for (int i = 0; i < NI; i++) {
        int t = lane + i * 64;
        if (t < tlen) { sc[i] = expf(sc[i] - m); sum += sc[i]; }
    }
    #pragma unroll
    for (int off = 32; off; off >>= 1) sum += __shfl_xor(sum, off);
    float inv = 1.f / sum;
    float oa[DK];
    #pragma unroll
    for (int dk = 0; dk < DK; dk++) oa[dk] = 0.f;
    #pragma unroll
    for (int i = 0; i < NI; i++) {
        int t = lane + i * 64;
        if (t < tlen) {
            const float* vr = kv + (size_t)(b * tlen + t) * 1024 + 512 + h * DK;
            float a = sc[i] * inv;
            #pragma unroll
            for (int dk = 0; dk < DK; dk++) oa[dk] += a * vr[dk];
        }
    }
    #pragma unroll
    for (int dk = 0; dk < DK; dk++) {
        float vv = oa[dk];
        #pragma unroll
        for (int off = 32; off; off >>= 1) vv += __shfl_xor(vv, off);
        if (lane == 0) o[(size_t)(b * 64 + qi) * D + h * DK + dk] = __float2bfloat16(vv);
    }
}

// ---------------- core causal attention: one wave per (b,h,pos); bf16 out ----------------
__global__ __launch_bounds__(64) void attn_core_k(
    const float* __restrict__ qkv, __hip_bfloat16* __restrict__ o)
{
    int p = blockIdx.x, h = blockIdx.y, b = blockIdx.z;
    int lane = threadIdx.x;
    __shared__ float qs[DK];
    if (lane < DK) qs[lane] = qkv[(size_t)(b * TTF + p) * 1536 + h * DK + lane];
    __syncthreads();
    int nk = p + 1;
    float sc[6];
    float m = -1e30f;
    #pragma unroll
    for (int i = 0; i < 6; i++) {
        sc[i] = 0.f;
        int t = lane + i * 64;
        if (t < nk) {
            const float* kr = qkv + (size_t)(b * TTF + t) * 1536 + 512 + h * DK;
            float d = 0.f;
            #pragma unroll
            for (int dk = 0; dk < DK; dk++) d += qs[dk] * kr[dk];
            d *= 0.17677669529663687f;
            sc[i] = d;
            m = fmaxf(m, d);
        }
    }
    #pragma unroll
    for (int off = 32; off; off >>= 1) m = fmaxf(m, __shfl_xor(m, off));
    float sum = 0.f;
    #pragma unroll
    for (int i = 0; i < 6; i++) {
        int t = lane + i * 64;
        if (t < nk) { sc[i] = expf(sc[i] - m); sum += sc[i]; }
    }
    #pragma unroll
    for (int off = 32; off; off >>= 1) sum += __shfl_xor(sum, off);
    float inv = 1.f / sum;
    float oa[DK];
    #pragma unroll
    for (int dk = 0; dk < DK; dk++) oa[dk] = 0.f;
    #pragma unroll
    for (int i = 0; i < 6; i++) {
        int t = lane + i * 64;
        if (t < nk) {
            const float* vr = qkv + (size_t)(b * TTF + t) * 1536 + 1024 + h * DK;
            float a = sc[i] * inv;
            #pragma unroll
            for (int dk = 0; dk < DK; dk++) oa[dk] += a * vr[dk];
        }
    }
    #pragma unroll
    for (int dk = 0; dk < DK; dk++) {
        float vv = oa[dk];
        #pragma unroll
        for (int off = 32; off; off >>= 1) vv += __shfl_xor(vv, off);
        if (lane == 0) o[(size_t)(b * TTF + p) * D + h * DK + dk] = __float2bfloat16(vv);
    }
}

// ---------------- tgt copy ----------------
__global__ __launch_bounds__(256) void tgt_k(const int* __restrict__ tids, float* __restrict__ out)
{
    int i = blockIdx.x * 256 + threadIdx.x;
    int b = i >> 8, c = i & 255;
    out[i] = (float)tids[b * 1024 + 768 + c];
}

extern "C" void kernel_launch(void* const* d_in, const int* in_sizes, int n_in,
                              void* d_out, int out_size, void* d_ws, size_t ws_size,
                              hipStream_t stream) {
    (void)in_sizes; (void)n_in; (void)out_size; (void)ws_size;
    const int*   input_ids  = (const int*)  d_in[0];
    const int*   target_ids = (const int*)  d_in[1];
    const float* emb_sem    = (const float*)d_in[2];
    const float* emb_pos    = (const float*)d_in[3];
    const float* lg_sem     = (const float*)d_in[4];
    const float* lg_pos     = (const float*)d_in[5];
    const float* lg_inw     = (const float*)d_in[6];
    const float* lg_inb     = (const float*)d_in[7];
    const float* lg_outw    = (const float*)d_in[8];
    const float* lg_outb    = (const float*)d_in[9];
    const float* lg_tok     = (const float*)d_in[10];
    const float* lg_lng     = (const float*)d_in[11];
    const float* lg_lnb     = (const float*)d_in[12];
    const float* md_sem     = (const float*)d_in[13];
    const float* md_pos     = (const float*)d_in[14];
    const float* md_inw     = (const float*)d_in[15];
    const float* md_inb     = (const float*)d_in[16];
    const float* md_outw    = (const float*)d_in[17];
    const float* md_outb    = (const float*)d_in[18];
    const float* md_tok     = (const float*)d_in[19];
    const float* md_lng     = (const float*)d_in[20];
    const float* md_lnb     = (const float*)d_in[21];
    const float* qkv_w      = (const float*)d_in[22];
    const float* qkv_b      = (const float*)d_in[23];
    const float* wo_w       = (const float*)d_in[24];
    const float* wo_b       = (const float*)d_in[25];
    const float* ln1_g      = (const float*)d_in[26];
    const float* ln1_b      = (const float*)d_in[27];
    const float* ln2_g      = (const float*)d_in[28];
    const float* ln2_b      = (const float*)d_in[29];
    const float* ff1_w      = (const float*)d_in[30];
    const float* ff1_b      = (const float*)d_in[31];
    const float* ff2_w      = (const float*)d_in[32];
    const float* ff2_b      = (const float*)d_in[33];
    const float* hd_lng     = (const float*)d_in[34];
    const float* hd_lnb     = (const float*)d_in[35];
    const float* hd_w       = (const float*)d_in[36];
    const float* hd_b       = (const float*)d_in[37];

    // ---- workspace layout ----
    float* x    = (float*)d_ws;              // 16*384*512   = 3,145,728 f32
    float* qkvb = x    + 3145728;            // 9,437,184 f32 (qkv / summarizer KV)
    float* so2  = qkvb + 9437184;            // 524,288 f32
    float* q_s  = so2  + 524288;             // 32,768 f32
    __hip_bfloat16* h_bf   = (__hip_bfloat16*)(q_s + 32768);   // 3,145,728 bf16
    __hip_bfloat16* a_bf   = h_bf   + 3145728;                 // 6,291,456 bf16 (embeds/attn-out/ff1-out)
    __hip_bfloat16* sumo_bf= a_bf   + 6291456;                 // 524,288 bf16
    __hip_bfloat16* w_qkv  = sumo_bf+ 524288;                  // 12,582,912
    __hip_bfloat16* w_wo   = w_qkv  + 12582912;                // 4,194,304
    __hip_bfloat16* w_ff1  = w_wo   + 4194304;                 // 8,388,608
    __hip_bfloat16* w_ff2  = w_ff1  + 8388608;                 // 8,388,608
    __hip_bfloat16* w_hd   = w_ff2  + 8388608;                 // 16,777,216
    __hip_bfloat16* w_lgin = w_hd   + 16777216;                // 786,432
    __hip_bfloat16* w_mdin = w_lgin + 786432;                  // 786,432
    __hip_bfloat16* w_lgout= w_mdin + 786432;                  // 262,144
    __hip_bfloat16* w_mdout= w_lgout+ 262144;                  // 262,144

    // ---- weight conversion (stream-ordered, once per call) ----
    cvt_k<<<12582912 / 2048, 256, 0, stream>>>(qkv_w, w_qkv, 12582912);
    cvt_k<<< 4194304 / 2048, 256, 0, stream>>>(wo_w,  w_wo,   4194304);
    cvt_k<<< 8388608 / 2048, 256, 0, stream>>>(ff1_w, w_ff1,  8388608);
    cvt_k<<< 8388608 / 2048, 256, 0, stream>>>(ff2_w, w_ff2,  8388608);
    cvt_k<<<16777216 / 2048, 256, 0, stream>>>(hd_w,  w_hd,  16777216);
    cvt_k<<<  786432 / 2048, 256, 0, stream>>>(lg_inw, w_lgin, 786432);
    cvt_k<<<  786432 / 2048, 256, 0, stream>>>(md_inw, w_mdin, 786432);
    cvt_k<<<  262144 / 2048, 256, 0, stream>>>(lg_outw, w_lgout, 262144);
    cvt_k<<<  262144 / 2048, 256, 0, stream>>>(md_outw, w_mdout, 262144);

    // ======== summarizer LG (tlen=512) ========
    embed_k<1><<<dim3(512, NB), 128, 0, stream>>>(input_ids, 1024, 0, lg_sem, lg_pos, a_bf, 512, 0);
    mgemm_k<<<dim3(8, 64), 256, 0, stream>>>(a_bf, w_lgin + 512 * 512, lg_inb + 512, qkvb, 8192, 1024, 512, 0);
    gemm_k<<<dim3(8, 1), 256, 0, stream>>>(lg_tok, lg_inw, lg_inb, q_s, 64, 512, 512);
    attn_sum_k<8><<<dim3(64, NHEAD, NB), 64, 0, stream>>>(q_s, qkvb, sumo_bf, 512);
    mgemm_k<<<dim3(4, 8), 256, 0, stream>>>(sumo_bf, w_lgout, lg_outb, so2, 1024, 512, 512, 0);
    ln_k<0><<<1024, 64, 0, stream>>>(so2, x, lg_lng, lg_lnb, 64, 64, 0, TTF, 0);

    // ======== summarizer MD (tlen=256) ========
    embed_k<1><<<dim3(256, NB), 128, 0, stream>>>(input_ids, 1024, 512, md_sem, md_pos, a_bf, 256, 0);
    mgemm_k<<<dim3(8, 32), 256, 0, stream>>>(a_bf, w_mdin + 512 * 512, md_inb + 512, qkvb, 4096, 1024, 512, 0);
    gemm_k<<<dim3(8, 1), 256, 0, stream>>>(md_tok, md_inw, md_inb, q_s, 64, 512, 512);
    attn_sum_k<4><<<dim3(64, NHEAD, NB), 64, 0, stream>>>(q_s, qkvb, sumo_bf, 256);
    mgemm_k<<<dim3(4, 8), 256, 0, stream>>>(sumo_bf, w_mdout, md_outb, so2, 1024, 512, 512, 0);
    ln_k<0><<<1024, 64, 0, stream>>>(so2, x, md_lng, md_lnb, 64, 64, 0, TTF, 64);

    // ======== core embeddings into x[:, 128:384, :] ========
    embed_k<0><<<dim3(256, NB), 128, 0, stream>>>(input_ids, 1024, 768, emb_sem, emb_pos, x, TTF, 128);

    // ======== 16 transformer layers ========
    for (int l = 0; l < NLAYER; l++) {
        ln_k<1><<<6144, 64, 0, stream>>>(x, h_bf, ln1_g + l * D, ln1_b + l * D, TTF, TTF, 0, TTF, 0);
        mgemm_k<<<dim3(12, 48), 256, 0, stream>>>(h_bf, w_qkv + (size_t)l * 1536 * 512, qkv_b + l * 1536, qkvb, 6144, 1536, 512, 0);
        attn_core_k<<<dim3(TTF, NHEAD, NB), 64, 0, stream>>>(qkvb, a_bf);
        mgemm_k<<<dim3(4, 48), 256, 0, stream>>>(a_bf, w_wo + (size_t)l * 512 * 512, wo_b + l * D, x, 6144, 512, 512, 1);
        ln_k<1><<<6144, 64, 0, stream>>>(x, h_bf, ln2_g + l * D, ln2_b + l * D, TTF, TTF, 0, TTF, 0);
        mgemm_k<<<dim3(8, 48), 256, 0, stream>>>(h_bf, w_ff1 + (size_t)l * 1024 * 512, ff1_b + l * FF, a_bf, 6144, 1024, 512, 2);
        mgemm_k<<<dim3(4, 48), 256, 0, stream>>>(a_bf, w_ff2 + (size_t)l * 512 * 1024, ff2_b + l * D, x, 6144, 512, 1024, 1);
    }

    // ======== head ========
    ln_k<1><<<4096, 64, 0, stream>>>(x, h_bf, hd_lng, hd_lnb, NCORE, TTF, 128, NCORE, 0);
    float* logits = (float*)d_out;
    mgemm_k<<<dim3(256, 32), 256, 0, stream>>>(h_bf, w_hd, hd_b, logits, 4096, VOC, 512, 0);
    tgt_k<<<16, 256, 0, stream>>>(target_ids, logits + (size_t)NB * NCORE * VOC);
}

// Round 3
// 3840.623 us; speedup vs baseline: 4.6707x; 3.2939x over previous
//
#include <hip/hip_runtime.h>
#include <hip/hip_bf16.h>
#include <math.h>

#define D 512
#define NHEAD 16
#define DK 32
#define NLAYER 16
#define FF 1024
#define VOC 32768
#define TTF 384
#define NCORE 256
#define NB 16

typedef __attribute__((ext_vector_type(8))) short bfrag;   // 8 bf16 (4 VGPRs)
typedef __attribute__((ext_vector_type(4))) float f32x4;

// ---------- async global->LDS, 16B per lane ----------
typedef __attribute__((address_space(3))) void lds_void;
typedef const __attribute__((address_space(1))) void gbl_void;
__device__ __forceinline__ void gload16(const void* g, void* l) {
    __builtin_amdgcn_global_load_lds((gbl_void*)g, (lds_void*)l, 16, 0, 0);
}

__device__ __forceinline__ float gelu_f(float v) {
    return 0.5f * v * (1.0f + erff(v * 0.70710678118654752f));
}

// ---------------- f32 -> bf16 convert ----------------
__global__ __launch_bounds__(256) void cvt_k(const float* __restrict__ in,
                                             __hip_bfloat16* __restrict__ out, int n)
{
    int i = (blockIdx.x * 256 + threadIdx.x) * 8;
    if (i >= n) return;
    float4 a = *reinterpret_cast<const float4*>(in + i);
    float4 b = *reinterpret_cast<const float4*>(in + i + 4);
    __align__(16) __hip_bfloat16 t[8];
    t[0] = __float2bfloat16(a.x); t[1] = __float2bfloat16(a.y);
    t[2] = __float2bfloat16(a.z); t[3] = __float2bfloat16(a.w);
    t[4] = __float2bfloat16(b.x); t[5] = __float2bfloat16(b.y);
    t[6] = __float2bfloat16(b.z); t[7] = __float2bfloat16(b.w);
    *reinterpret_cast<uint4*>(out + i) = *reinterpret_cast<const uint4*>(t);
}

// ---------------- embedding gather ----------------
template<int OB>
__global__ __launch_bounds__(128) void embed_k(
    const int* __restrict__ ids, int id_stride, int id_off,
    const float* __restrict__ sem, const float* __restrict__ pos,
    void* __restrict__ out, int out_stride, int out_off)
{
    int t = blockIdx.x, b = blockIdx.y, tid = threadIdx.x;
    int id = ids[b * id_stride + id_off + t];
    const float4* s4 = reinterpret_cast<const float4*>(sem + (size_t)id * D);
    const float4* p4 = reinterpret_cast<const float4*>(pos + (size_t)t * D);
    size_t row = (size_t)(b * out_stride + out_off + t) * D;
    float4 a = s4[tid], p = p4[tid];
    float v0 = a.x + p.x, v1 = a.y + p.y, v2 = a.z + p.z, v3 = a.w + p.w;
    if (OB) {
        __hip_bfloat16* o = (__hip_bfloat16*)out + row + tid * 4;
        o[0] = __float2bfloat16(v0); o[1] = __float2bfloat16(v1);
        o[2] = __float2bfloat16(v2); o[3] = __float2bfloat16(v3);
    } else {
        float4* o4 = reinterpret_cast<float4*>((float*)out + row);
        o4[tid] = make_float4(v0, v1, v2, v3);
    }
}

// ---------------- bf16 MFMA GEMM: C(M,N) = A(M,K) @ W(N,K)^T + bias ----------------
// flags: 0 = f32 out, 1 = f32 out += (residual), 2 = bf16 out + exact GELU, 3 = bf16 out
__global__ __launch_bounds__(256) void mgemm_k(
    const __hip_bfloat16* __restrict__ A, const __hip_bfloat16* __restrict__ W,
    const float* __restrict__ bias, void* __restrict__ C,
    int M, int N, int K, int flags)
{
    __shared__ __align__(16) __hip_bfloat16 sA[128][64];
    __shared__ __align__(16) __hip_bfloat16 sB[128][64];
    int tid = threadIdx.x;
    int w = tid >> 6, lane = tid & 63;
    int wr = w >> 1, wc = w & 1;
    int row0 = blockIdx.y * 128, col0 = blockIdx.x * 128;

    const __hip_bfloat16* gA[4];
    const __hip_bfloat16* gB[4];
    #pragma unroll
    for (int r = 0; r < 4; r++) {
        int trow = r * 32 + w * 8 + (lane >> 3);
        int tcol = (lane & 7) * 8;
        gA[r] = A + (size_t)(row0 + trow) * K + tcol;
        gB[r] = W + (size_t)(col0 + trow) * K + tcol;
    }
    __hip_bfloat16* sAf = &sA[0][0];
    __hip_bfloat16* sBf = &sB[0][0];

    f32x4 acc[4][4];
    #pragma unroll
    for (int m = 0; m < 4; m++)
        #pragma unroll
        for (int n = 0; n < 4; n++) acc[m][n] = (f32x4){0.f, 0.f, 0.f, 0.f};

    int cr = lane >> 4;
    int cc = lane & 15;

    for (int k0 = 0; k0 < K; k0 += 64) {
        #pragma unroll
        for (int r = 0; r < 4; r++) {
            gload16(gA[r] + k0, sAf + r * 2048 + w * 512);
            gload16(gB[r] + k0, sBf + r * 2048 + w * 512);
        }
        __syncthreads();
        #pragma unroll
        for (int ks = 0; ks < 2; ks++) {
            int colk = ks * 32 + cr * 8;
            bfrag af[4], bf[4];
            #pragma unroll
            for (int m = 0; m < 4; m++)
                af[m] = *reinterpret_cast<const bfrag*>(&sA[wr * 64 + m * 16 + cc][colk]);
            #pragma unroll
            for (int n = 0; n < 4; n++)
                bf[n] = *reinterpret_cast<const bfrag*>(&sB[wc * 64 + n * 16 + cc][colk]);
            #pragma unroll
            for (int m = 0; m < 4; m++)
                #pragma unroll
                for (int n = 0; n < 4; n++)
                    acc[m][n] = __builtin_amdgcn_mfma_f32_16x16x32_bf16(af[m], bf[n], acc[m][n], 0, 0, 0);
        }
        __syncthreads();
    }

    #pragma unroll
    for (int m = 0; m < 4; m++) {
        int rg = row0 + wr * 64 + m * 16 + cr * 4;
        #pragma unroll
        for (int n = 0; n < 4; n++) {
            int cg = col0 + wc * 64 + n * 16 + cc;
            float bs = bias[cg];
            #pragma unroll
            for (int j = 0; j < 4; j++) {
                float v = acc[m][n][j] + bs;
                size_t off = (size_t)(rg + j) * N + cg;
                if (flags == 1)      ((float*)C)[off] += v;
                else if (flags == 2) ((__hip_bfloat16*)C)[off] = __float2bfloat16(gelu_f(v));
                else if (flags == 3) ((__hip_bfloat16*)C)[off] = __float2bfloat16(v);
                else                 ((float*)C)[off] = v;
            }
        }
    }
}

// ---------------- small fp32 GEMM (64-row query projections) ----------------
__global__ __launch_bounds__(256) void gemm_k(
    const float* __restrict__ A, const float* __restrict__ W,
    const float* __restrict__ bias, float* __restrict__ C,
    int M, int N, int K)
{
    __shared__ float As[16][68];
    __shared__ float Ws[16][68];
    int tid = threadIdx.x;
    int row0 = blockIdx.y * 64;
    int col0 = blockIdx.x * 64;
    int lr = tid >> 2;
    int lk = (tid & 3) * 4;
    int tx = tid & 15, ty = tid >> 4;
    float acc[4][4] = {};
    const float* Ap = A + (size_t)(row0 + lr) * K + lk;
    const float* Wp = W + (size_t)(col0 + lr) * K + lk;
    for (int k0 = 0; k0 < K; k0 += 16) {
        float4 a4 = *reinterpret_cast<const float4*>(Ap + k0);
        float4 w4 = *reinterpret_cast<const float4*>(Wp + k0);
        As[lk + 0][lr] = a4.x; As[lk + 1][lr] = a4.y; As[lk + 2][lr] = a4.z; As[lk + 3][lr] = a4.w;
        Ws[lk + 0][lr] = w4.x; Ws[lk + 1][lr] = w4.y; Ws[lk + 2][lr] = w4.z; Ws[lk + 3][lr] = w4.w;
        __syncthreads();
        #pragma unroll
        for (int kk = 0; kk < 16; kk++) {
            float4 av = *reinterpret_cast<const float4*>(&As[kk][ty * 4]);
            float4 wv = *reinterpret_cast<const float4*>(&Ws[kk][tx * 4]);
            float avv[4] = {av.x, av.y, av.z, av.w};
            float wvv[4] = {wv.x, wv.y, wv.z, wv.w};
            #pragma unroll
            for (int i = 0; i < 4; i++)
                #pragma unroll
                for (int j = 0; j < 4; j++)
                    acc[i][j] += avv[i] * wvv[j];
        }
        __syncthreads();
    }
    #pragma unroll
    for (int i = 0; i < 4; i++) {
        int r = row0 + ty * 4 + i;
        #pragma unroll
        for (int j = 0; j < 4; j++) {
            int c = col0 + tx * 4 + j;
            C[(size_t)r * N + c] = acc[i][j] + bias[c];
        }
    }
}

// ---------------- layernorm ----------------
template<int OB>
__global__ __launch_bounds__(64) void ln_k(
    const float* __restrict__ in, void* __restrict__ out,
    const float* __restrict__ g, const float* __restrict__ bt,
    int rpb, int in_stride, int in_off, int out_stride, int out_off)
{
    int r = blockIdx.x;
    int b = r / rpb, t = r % rpb;
    const float* xr = in + (size_t)(b * in_stride + in_off + t) * D;
    size_t orow = (size_t)(b * out_stride + out_off + t) * D;
    int lane = threadIdx.x;
    float v[8];
    float s = 0.f;
    #pragma unroll
    for (int i = 0; i < 8; i++) { v[i] = xr[lane + i * 64]; s += v[i]; }
    #pragma unroll
    for (int off = 32; off; off >>= 1) s += __shfl_xor(s, off);
    float mu = s * (1.f / 512.f);
    float vs = 0.f;
    #pragma unroll
    for (int i = 0; i < 8; i++) { float d = v[i] - mu; vs += d * d; }
    #pragma unroll
    for (int off = 32; off; off >>= 1) vs += __shfl_xor(vs, off);
    float rstd = rsqrtf(vs * (1.f / 512.f) + 1e-5f);
    #pragma unroll
    for (int i = 0; i < 8; i++) {
        int c = lane + i * 64;
        float y = (v[i] - mu) * rstd * g[c] + bt[c];
        if (OB) ((__hip_bfloat16*)out)[orow + c] = __float2bfloat16(y);
        else    ((float*)out)[orow + c] = y;
    }
}

// ---------------- fused MFMA causal attention ----------------
// One block per (h, b); 8 waves. qkv: (B*384, 1536) bf16, cols [0,512)=q, [512,1024)=k, [1024,1536)=v.
// Wave w handles q-tiles {w, 15-w, 16+w} (16 queries each). K/Vt staged in LDS in
// MFMA-fragment-contiguous layout (ds_read_b128 at lane*16 => conflict-free).
__global__ __launch_bounds__(512) void fattn_k(
    const __hip_bfloat16* __restrict__ qkv, __hip_bfloat16* __restrict__ o)
{
    __shared__ __align__(16) __hip_bfloat16 Kl[24 * 512];   // [kt][lane][8] : K[kt*16+(f&15)][(f>>4)*8+j]
    __shared__ __align__(16) __hip_bfloat16 Vl[24 * 512];   // [ks*2+dt][lane][8] : V[ks*32+(f>>4)*8+j][dt*16+(f&15)]
    __shared__ __align__(16) __hip_bfloat16 Pl[8 * 512];    // per-wave [lane][8] : P[q0+(f&15)][ks*32+(f>>4)*8+j]
    int h = blockIdx.x, b = blockIdx.y;
    int tid = threadIdx.x, w = tid >> 6, l = tid & 63;
    const size_t base = (size_t)b * TTF * 1536 + h * DK;

    // ---- stage K (vector writes) and V (transpose scatter) ----
    for (int it = 0; it < 3; it++) {
        int item = it * 512 + tid;            // 0..1535 = key*4 + dkgroup
        int key = item >> 2, dg = item & 3;
        uint4 k4 = *reinterpret_cast<const uint4*>(qkv + base + (size_t)key * 1536 + 512 + dg * 8);
        *reinterpret_cast<uint4*>(&Kl[((key >> 4) * 64 + dg * 16 + (key & 15)) * 8]) = k4;
        uint4 v4 = *reinterpret_cast<const uint4*>(qkv + base + (size_t)key * 1536 + 1024 + dg * 8);
        const ushort* ve = reinterpret_cast<const ushort*>(&v4);
        #pragma unroll
        for (int e = 0; e < 8; e++) {
            int dk = dg * 8 + e;
            int f = (((key & 31) >> 3) << 4) | (dk & 15);
            int idx = (((key >> 5) << 1) + (dk >> 4)) * 512 + f * 8 + (key & 7);
            reinterpret_cast<ushort*>(Vl)[idx] = ve[e];
        }
    }
    __syncthreads();

    const float sc = 0.17677669529663687f;   // 1/sqrt(32)
    __hip_bfloat16* pw = Pl + w * 512;

    for (int iq = 0; iq < 3; iq++) {
        int qt = (iq == 0) ? w : (iq == 1 ? 15 - w : 16 + w);
        int q0 = qt * 16;
        bfrag qf = *reinterpret_cast<const bfrag*>(qkv + base + (size_t)(q0 + (l & 15)) * 1536 + (l >> 4) * 8);
        f32x4 oa0 = (f32x4){0.f, 0.f, 0.f, 0.f};
        f32x4 oa1 = (f32x4){0.f, 0.f, 0.f, 0.f};
        float mrun[4], lrun[4];
        #pragma unroll
        for (int jj = 0; jj < 4; jj++) { mrun[jj] = -3.0e38f; lrun[jj] = 0.f; }
        int ksmax = (q0 + 15) >> 5;

        for (int ks = 0; ks <= ksmax; ks++) {
            bfrag kf0 = *reinterpret_cast<const bfrag*>(&Kl[(ks * 2 + 0) * 512 + l * 8]);
            bfrag kf1 = *reinterpret_cast<const bfrag*>(&Kl[(ks * 2 + 1) * 512 + l * 8]);
            f32x4 z = (f32x4){0.f, 0.f, 0.f, 0.f};
            f32x4 s0 = __builtin_amdgcn_mfma_f32_16x16x32_bf16(qf, kf0, z, 0, 0, 0);
            f32x4 s1 = __builtin_amdgcn_mfma_f32_16x16x32_bf16(qf, kf1, z, 0, 0, 0);
            if (ks == ksmax) {   // causal mask (diagonal slice only)
                #pragma unroll
                for (int jj = 0; jj < 4; jj++) {
                    int q = q0 + ((l >> 4) << 2) + jj;
                    if (ks * 32 + (l & 15) > q)      s0[jj] = -3.0e38f;
                    if (ks * 32 + 16 + (l & 15) > q) s1[jj] = -3.0e38f;
                }
            }
            float p0[4], p1[4], ps[4];
            #pragma unroll
            for (int jj = 0; jj < 4; jj++) {
                float sm = fmaxf(s0[jj], s1[jj]);
                #pragma unroll
                for (int off = 1; off <= 8; off <<= 1) sm = fmaxf(sm, __shfl_xor(sm, off));
                float mnew = fmaxf(mrun[jj], sm);
                float f = __expf((mrun[jj] - mnew) * sc);
                mrun[jj] = mnew;
                lrun[jj] *= f;
                oa0[jj] *= f; oa1[jj] *= f;
                p0[jj] = __expf((s0[jj] - mnew) * sc);
                p1[jj] = __expf((s1[jj] - mnew) * sc);
                ps[jj] = p0[jj] + p1[jj];
            }
            #pragma unroll
            for (int jj = 0; jj < 4; jj++) {
                float t = ps[jj];
                #pragma unroll
                for (int off = 1; off <= 8; off <<= 1) t += __shfl_xor(t, off);
                lrun[jj] += t;
            }
            // write P chunk (unnormalized, bf16) into per-wave transpose buffer
            #pragma unroll
            for (int jj = 0; jj < 4; jj++) {
                int ql = ((l >> 4) << 2) + jj;
                int kl0 = l & 15, kl1 = 16 + (l & 15);
                pw[((kl0 >> 3) * 16 + ql) * 8 + (kl0 & 7)] = __float2bfloat16(p0[jj]);
                pw[((kl1 >> 3) * 16 + ql) * 8 + (kl1 & 7)] = __float2bfloat16(p1[jj]);
            }
            bfrag pf  = *reinterpret_cast<const bfrag*>(&pw[l * 8]);
            bfrag vf0 = *reinterpret_cast<const bfrag*>(&Vl[(ks * 2 + 0) * 512 + l * 8]);
            bfrag vf1 = *reinterpret_cast<const bfrag*>(&Vl[(ks * 2 + 1) * 512 + l * 8]);
            oa0 = __builtin_amdgcn_mfma_f32_16x16x32_bf16(pf, vf0, oa0, 0, 0, 0);
            oa1 = __builtin_amdgcn_mfma_f32_16x16x32_bf16(pf, vf1, oa1, 0, 0, 0);
        }
        #pragma unroll
        for (int jj = 0; jj < 4; jj++) {
            float inv = 1.0f / lrun[jj];
            int q = q0 + ((l >> 4) << 2) + jj;
            size_t orow = ((size_t)b * TTF + q) * D + h * DK;
            o[orow + (l & 15)]      = __float2bfloat16(oa0[jj] * inv);
            o[orow + 16 + (l & 15)] = __float2bfloat16(oa1[jj] * inv);
        }
    }
}

// ---------------- summarizer attention (unchanged, f32) ----------------
template<int NI>
__global__ __launch_bounds__(64) void attn_sum_k(
    const float* __restrict__ q, const float* __restrict__ kv,
    __hip_bfloat16* __restrict__ o, int tlen)
{
    int qi = blockIdx.x, h = blockIdx.y, b = blockIdx.z;
    int lane = threadIdx.x;
    __shared__ float qs[DK];
    if (lane < DK) qs[lane] = q[(size_t)qi * D + h * DK + lane];
    __syncthreads();
    float sc[NI];
    float m = -1e30f;
    #pragma unroll
    for (int i = 0; i < NI; i++) {
        sc[i] = 0.f;
        int t = lane + i * 64;
        if (t < tlen) {
            const float* kr = kv + (size_t)(b * tlen + t) * 1024 + h * DK;
            float d = 0.f;
            #pragma unroll
            for (int dk = 0; dk < DK; dk++) d += qs[dk] * kr[dk];
            d *= 0.17677669529663687f;
            sc[i] = d;
            m = fmaxf(m, d);
        }
    }
    #pragma unroll
    for (int off = 32; off; off >>= 1) m = fmaxf(m, __shfl_xor(m, off));
    float sum = 0.f;
    #pragma unroll
    for (int i = 0; i < NI; i++) {
        int t = lane + i * 64;
        if (t < tlen) { sc[i] = expf(sc[i] - m); sum += sc[i]; }
    }
    #pragma unroll
    for (int off = 32; off; off >>= 1) sum += __shfl_xor(sum, off);
    float inv = 1.f / sum;
    float oa[DK];
    #pragma unroll
    for (int dk = 0; dk < DK; dk++) oa[dk] = 0.f;
    #pragma unroll
    for (int i = 0; i < NI; i++) {
        int t = lane + i * 64;
        if (t < tlen) {
            const float* vr = kv + (size_t)(b * tlen + t) * 1024 + 512 + h * DK;
            float a = sc[i] * inv;
            #pragma unroll
            for (int dk = 0; dk < DK; dk++) oa[dk] += a * vr[dk];
        }
    }
    #pragma unroll
    for (int dk = 0; dk < DK; dk++) {
        float vv = oa[dk];
        #pragma unroll
        for (int off = 32; off; off >>= 1) vv += __shfl_xor(vv, off);
        if (lane == 0) o[(size_t)(b * 64 + qi) * D + h * DK + dk] = __float2bfloat16(vv);
    }
}

// ---------------- tgt copy ----------------
__global__ __launch_bounds__(256) void tgt_k(const int* __restrict__ tids, float* __restrict__ out)
{
    int i = blockIdx.x * 256 + threadIdx.x;
    int b = i >> 8, c = i & 255;
    out[i] = (float)tids[b * 1024 + 768 + c];
}

extern "C" void kernel_launch(void* const* d_in, const int* in_sizes, int n_in,
                              void* d_out, int out_size, void* d_ws, size_t ws_size,
                              hipStream_t stream) {
    (void)in_sizes; (void)n_in; (void)out_size; (void)ws_size;
    const int*   input_ids  = (const int*)  d_in[0];
    const int*   target_ids = (const int*)  d_in[1];
    const float* emb_sem    = (const float*)d_in[2];
    const float* emb_pos    = (const float*)d_in[3];
    const float* lg_sem     = (const float*)d_in[4];
    const float* lg_pos     = (const float*)d_in[5];
    const float* lg_inw     = (const float*)d_in[6];
    const float* lg_inb     = (const float*)d_in[7];
    const float* lg_outw    = (const float*)d_in[8];
    const float* lg_outb    = (const float*)d_in[9];
    const float* lg_tok     = (const float*)d_in[10];
    const float* lg_lng     = (const float*)d_in[11];
    const float* lg_lnb     = (const float*)d_in[12];
    const float* md_sem     = (const float*)d_in[13];
    const float* md_pos     = (const float*)d_in[14];
    const float* md_inw     = (const float*)d_in[15];
    const float* md_inb     = (const float*)d_in[16];
    const float* md_outw    = (const float*)d_in[17];
    const float* md_outb    = (const float*)d_in[18];
    const float* md_tok     = (const float*)d_in[19];
    const float* md_lng     = (const float*)d_in[20];
    const float* md_lnb     = (const float*)d_in[21];
    const float* qkv_w      = (const float*)d_in[22];
    const float* qkv_b      = (const float*)d_in[23];
    const float* wo_w       = (const float*)d_in[24];
    const float* wo_b       = (const float*)d_in[25];
    const float* ln1_g      = (const float*)d_in[26];
    const float* ln1_b      = (const float*)d_in[27];
    const float* ln2_g      = (const float*)d_in[28];
    const float* ln2_b      = (const float*)d_in[29];
    const float* ff1_w      = (const float*)d_in[30];
    const float* ff1_b      = (const float*)d_in[31];
    const float* ff2_w      = (const float*)d_in[32];
    const float* ff2_b      = (const float*)d_in[33];
    const float* hd_lng     = (const float*)d_in[34];
    const float* hd_lnb     = (const float*)d_in[35];
    const float* hd_w       = (const float*)d_in[36];
    const float* hd_b       = (const float*)d_in[37];

    // ---- workspace layout ----
    float* x    = (float*)d_ws;              // 3,145,728 f32
    float* qkvb = x    + 3145728;            // 9,437,184 f32 (summarizer KV; layers reuse as bf16 qkv)
    float* so2  = qkvb + 9437184;            // 524,288 f32
    float* q_s  = so2  + 524288;             // 32,768 f32
    __hip_bfloat16* qkv_bf = (__hip_bfloat16*)qkvb;            // alias: 9,437,184 bf16 (fits in half)
    __hip_bfloat16* h_bf   = (__hip_bfloat16*)(q_s + 32768);   // 3,145,728 bf16
    __hip_bfloat16* a_bf   = h_bf   + 3145728;                 // 6,291,456 bf16
    __hip_bfloat16* sumo_bf= a_bf   + 6291456;                 // 524,288 bf16
    __hip_bfloat16* w_qkv  = sumo_bf+ 524288;                  // 12,582,912
    __hip_bfloat16* w_wo   = w_qkv  + 12582912;                // 4,194,304
    __hip_bfloat16* w_ff1  = w_wo   + 4194304;                 // 8,388,608
    __hip_bfloat16* w_ff2  = w_ff1  + 8388608;                 // 8,388,608
    __hip_bfloat16* w_hd   = w_ff2  + 8388608;                 // 16,777,216
    __hip_bfloat16* w_lgin = w_hd   + 16777216;                // 786,432
    __hip_bfloat16* w_mdin = w_lgin + 786432;                  // 786,432
    __hip_bfloat16* w_lgout= w_mdin + 786432;                  // 262,144
    __hip_bfloat16* w_mdout= w_lgout+ 262144;                  // 262,144

    // ---- weight conversion ----
    cvt_k<<<12582912 / 2048, 256, 0, stream>>>(qkv_w, w_qkv, 12582912);
    cvt_k<<< 4194304 / 2048, 256, 0, stream>>>(wo_w,  w_wo,   4194304);
    cvt_k<<< 8388608 / 2048, 256, 0, stream>>>(ff1_w, w_ff1,  8388608);
    cvt_k<<< 8388608 / 2048, 256, 0, stream>>>(ff2_w, w_ff2,  8388608);
    cvt_k<<<16777216 / 2048, 256, 0, stream>>>(hd_w,  w_hd,  16777216);
    cvt_k<<<  786432 / 2048, 256, 0, stream>>>(lg_inw, w_lgin, 786432);
    cvt_k<<<  786432 / 2048, 256, 0, stream>>>(md_inw, w_mdin, 786432);
    cvt_k<<<  262144 / 2048, 256, 0, stream>>>(lg_outw, w_lgout, 262144);
    cvt_k<<<  262144 / 2048, 256, 0, stream>>>(md_outw, w_mdout, 262144);

    // ======== summarizer LG (tlen=512) ========
    embed_k<1><<<dim3(512, NB), 128, 0, stream>>>(input_ids, 1024, 0, lg_sem, lg_pos, a_bf, 512, 0);
    mgemm_k<<<dim3(8, 64), 256, 0, stream>>>(a_bf, w_lgin + 512 * 512, lg_inb + 512, qkvb, 8192, 1024, 512, 0);
    gemm_k<<<dim3(8, 1), 256, 0, stream>>>(lg_tok, lg_inw, lg_inb, q_s, 64, 512, 512);
    attn_sum_k<8><<<dim3(64, NHEAD, NB), 64, 0, stream>>>(q_s, qkvb, sumo_bf, 512);
    mgemm_k<<<dim3(4, 8), 256, 0, stream>>>(sumo_bf, w_lgout, lg_outb, so2, 1024, 512, 512, 0);
    ln_k<0><<<1024, 64, 0, stream>>>(so2, x, lg_lng, lg_lnb, 64, 64, 0, TTF, 0);

    // ======== summarizer MD (tlen=256) ========
    embed_k<1><<<dim3(256, NB), 128, 0, stream>>>(input_ids, 1024, 512, md_sem, md_pos, a_bf, 256, 0);
    mgemm_k<<<dim3(8, 32), 256, 0, stream>>>(a_bf, w_mdin + 512 * 512, md_inb + 512, qkvb, 4096, 1024, 512, 0);
    gemm_k<<<dim3(8, 1), 256, 0, stream>>>(md_tok, md_inw, md_inb, q_s, 64, 512, 512);
    attn_sum_k<4><<<dim3(64, NHEAD, NB), 64, 0, stream>>>(q_s, qkvb, sumo_bf, 256);
    mgemm_k<<<dim3(4, 8), 256, 0, stream>>>(sumo_bf, w_mdout, md_outb, so2, 1024, 512, 512, 0);
    ln_k<0><<<1024, 64, 0, stream>>>(so2, x, md_lng, md_lnb, 64, 64, 0, TTF, 64);

    // ======== core embeddings into x[:, 128:384, :] ========
    embed_k<0><<<dim3(256, NB), 128, 0, stream>>>(input_ids, 1024, 768, emb_sem, emb_pos, x, TTF, 128);

    // ======== 16 transformer layers ========
    for (int l = 0; l < NLAYER; l++) {
        ln_k<1><<<6144, 64, 0, stream>>>(x, h_bf, ln1_g + l * D, ln1_b + l * D, TTF, TTF, 0, TTF, 0);
        mgemm_k<<<dim3(12, 48), 256, 0, stream>>>(h_bf, w_qkv + (size_t)l * 1536 * 512, qkv_b + l * 1536, qkv_bf, 6144, 1536, 512, 3);
        fattn_k<<<dim3(NHEAD, NB), 512, 0, stream>>>(qkv_bf, a_bf);
        mgemm_k<<<dim3(4, 48), 256, 0, stream>>>(a_bf, w_wo + (size_t)l * 512 * 512, wo_b + l * D, x, 6144, 512, 512, 1);
        ln_k<1><<<6144, 64, 0, stream>>>(x, h_bf, ln2_g + l * D, ln2_b + l * D, TTF, TTF, 0, TTF, 0);
        mgemm_k<<<dim3(8, 48), 256, 0, stream>>>(h_bf, w_ff1 + (size_t)l * 1024 * 512, ff1_b + l * FF, a_bf, 6144, 1024, 512, 2);
        mgemm_k<<<dim3(4, 48), 256, 0, stream>>>(a_bf, w_ff2 + (size_t)l * 512 * 1024, ff2_b + l * D, x, 6144, 512, 1024, 1);
    }

    // ======== head ========
    ln_k<1><<<4096, 64, 0, stream>>>(x, h_bf, hd_lng, hd_lnb, NCORE, TTF, 128, NCORE, 0);
    float* logits = (float*)d_out;
    mgemm_k<<<dim3(256, 32), 256, 0, stream>>>(h_bf, w_hd, hd_b, logits, 4096, VOC, 512, 0);
    tgt_k<<<16, 256, 0, stream>>>(target_ids, logits + (size_t)NB * NCORE * VOC);
}

// Round 4
// 3724.522 us; speedup vs baseline: 4.8163x; 1.0312x over previous
//
#include <hip/hip_runtime.h>
#include <hip/hip_bf16.h>
#include <math.h>

#define D 512
#define NHEAD 16
#define DK 32
#define NLAYER 16
#define FF 1024
#define VOC 32768
#define TTF 384
#define NCORE 256
#define NB 16

typedef __attribute__((ext_vector_type(8))) short bfrag;   // 8 bf16 (4 VGPRs)
typedef __attribute__((ext_vector_type(4))) float f32x4;

// ---------- async global->LDS, 16B per lane ----------
typedef __attribute__((address_space(3))) void lds_void;
typedef const __attribute__((address_space(1))) void gbl_void;
__device__ __forceinline__ void gload16(const void* g, void* l) {
    __builtin_amdgcn_global_load_lds((gbl_void*)g, (lds_void*)l, 16, 0, 0);
}

__device__ __forceinline__ float gelu_f(float v) {
    return 0.5f * v * (1.0f + erff(v * 0.70710678118654752f));
}

// ---------------- f32 -> bf16 convert ----------------
__global__ __launch_bounds__(256) void cvt_k(const float* __restrict__ in,
                                             __hip_bfloat16* __restrict__ out, int n)
{
    int i = (blockIdx.x * 256 + threadIdx.x) * 8;
    if (i >= n) return;
    float4 a = *reinterpret_cast<const float4*>(in + i);
    float4 b = *reinterpret_cast<const float4*>(in + i + 4);
    __align__(16) __hip_bfloat16 t[8];
    t[0] = __float2bfloat16(a.x); t[1] = __float2bfloat16(a.y);
    t[2] = __float2bfloat16(a.z); t[3] = __float2bfloat16(a.w);
    t[4] = __float2bfloat16(b.x); t[5] = __float2bfloat16(b.y);
    t[6] = __float2bfloat16(b.z); t[7] = __float2bfloat16(b.w);
    *reinterpret_cast<uint4*>(out + i) = *reinterpret_cast<const uint4*>(t);
}

// ---------------- embedding gather ----------------
template<int OB>
__global__ __launch_bounds__(128) void embed_k(
    const int* __restrict__ ids, int id_stride, int id_off,
    const float* __restrict__ sem, const float* __restrict__ pos,
    void* __restrict__ out, int out_stride, int out_off)
{
    int t = blockIdx.x, b = blockIdx.y, tid = threadIdx.x;
    int id = ids[b * id_stride + id_off + t];
    const float4* s4 = reinterpret_cast<const float4*>(sem + (size_t)id * D);
    const float4* p4 = reinterpret_cast<const float4*>(pos + (size_t)t * D);
    size_t row = (size_t)(b * out_stride + out_off + t) * D;
    float4 a = s4[tid], p = p4[tid];
    float v0 = a.x + p.x, v1 = a.y + p.y, v2 = a.z + p.z, v3 = a.w + p.w;
    if (OB) {
        __hip_bfloat16* o = (__hip_bfloat16*)out + row + tid * 4;
        o[0] = __float2bfloat16(v0); o[1] = __float2bfloat16(v1);
        o[2] = __float2bfloat16(v2); o[3] = __float2bfloat16(v3);
    } else {
        float4* o4 = reinterpret_cast<float4*>((float*)out + row);
        o4[tid] = make_float4(v0, v1, v2, v3);
    }
}

// ---------------- bf16 MFMA GEMM: C(M,N) = A(M,K) @ W(N,K)^T + bias ----------------
// 128x128 tile, 4 waves, BK=64. Double-buffered LDS with counted-vmcnt prefetch:
// per K-tile: issue next-tile gload_lds -> s_waitcnt vmcnt(8) (next 8 stay in flight)
// -> barrier -> ds_read+MFMA -> barrier. Raw s_barrier (no __syncthreads vmcnt(0) drain).
// flags: 0=f32, 1=f32 += (residual), 2=bf16+GELU, 3=bf16, 4=f32 nontemporal (logits)
__global__ __launch_bounds__(256) void mgemm_k(
    const __hip_bfloat16* __restrict__ A, const __hip_bfloat16* __restrict__ W,
    const float* __restrict__ bias, void* __restrict__ C,
    int M, int N, int K, int flags)
{
    __shared__ __align__(16) __hip_bfloat16 sA[2][128][64];
    __shared__ __align__(16) __hip_bfloat16 sB[2][128][64];
    int tid = threadIdx.x;
    int w = tid >> 6, lane = tid & 63;
    int wr = w >> 1, wc = w & 1;

    // bijective XCD swizzle (m204): each XCD gets a contiguous chunk of block space
    int nbx = gridDim.x;
    int nwg = nbx * gridDim.y;
    int bid0 = blockIdx.y * nbx + blockIdx.x;
    int bid = bid0;
    if (nwg >= 8) {
        int q = nwg >> 3, r = nwg & 7;
        int xcd = bid0 & 7, lb = bid0 >> 3;
        bid = (xcd < r ? xcd * (q + 1) : r * (q + 1) + (xcd - r) * q) + lb;
    }
    int bx = bid % nbx, by = bid / nbx;
    int row0 = by * 128, col0 = bx * 128;

    const __hip_bfloat16* gA[4];
    const __hip_bfloat16* gB[4];
    #pragma unroll
    for (int r = 0; r < 4; r++) {
        int trow = r * 32 + w * 8 + (lane >> 3);
        int tcol = (lane & 7) * 8;
        gA[r] = A + (size_t)(row0 + trow) * K + tcol;
        gB[r] = W + (size_t)(col0 + trow) * K + tcol;
    }

    f32x4 acc[4][4];
    #pragma unroll
    for (int m = 0; m < 4; m++)
        #pragma unroll
        for (int n = 0; n < 4; n++) acc[m][n] = (f32x4){0.f, 0.f, 0.f, 0.f};

    int cr = lane >> 4;
    int cc = lane & 15;

    auto stage = [&](int buf, int k0) {
        __hip_bfloat16* dstA = &sA[buf][0][0] + w * 512;
        __hip_bfloat16* dstB = &sB[buf][0][0] + w * 512;
        #pragma unroll
        for (int r = 0; r < 4; r++) {
            gload16(gA[r] + k0, dstA + r * 2048);
            gload16(gB[r] + k0, dstB + r * 2048);
        }
    };

    stage(0, 0);                      // prologue: first tile in flight
    for (int k0 = 0; k0 < K; k0 += 64) {
        int p = (k0 >> 6) & 1;
        bool more = (k0 + 64 < K);
        if (more) {
            stage(p ^ 1, k0 + 64);    // 8 more loads in flight (16 total)
            asm volatile("s_waitcnt vmcnt(8)" ::: "memory");   // current tile landed
        } else {
            asm volatile("s_waitcnt vmcnt(0)" ::: "memory");
        }
        __builtin_amdgcn_sched_barrier(0);
        __builtin_amdgcn_s_barrier();          // all waves' current tile visible
        __builtin_amdgcn_sched_barrier(0);

        #pragma unroll
        for (int ks = 0; ks < 2; ks++) {
            int colk = ks * 32 + cr * 8;
            bfrag af[4], bf[4];
            #pragma unroll
            for (int m = 0; m < 4; m++)
                af[m] = *reinterpret_cast<const bfrag*>(&sA[p][wr * 64 + m * 16 + cc][colk]);
            #pragma unroll
            for (int n = 0; n < 4; n++)
                bf[n] = *reinterpret_cast<const bfrag*>(&sB[p][wc * 64 + n * 16 + cc][colk]);
            #pragma unroll
            for (int m = 0; m < 4; m++)
                #pragma unroll
                for (int n = 0; n < 4; n++)
                    acc[m][n] = __builtin_amdgcn_mfma_f32_16x16x32_bf16(af[m], bf[n], acc[m][n], 0, 0, 0);
        }
        __builtin_amdgcn_sched_barrier(0);
        __builtin_amdgcn_s_barrier();          // this buffer may be overwritten next iter
        __builtin_amdgcn_sched_barrier(0);
    }

    // epilogue. C/D layout: col = lane&15, row = (lane>>4)*4 + j
    #pragma unroll
    for (int m = 0; m < 4; m++) {
        int rg = row0 + wr * 64 + m * 16 + cr * 4;
        #pragma unroll
        for (int n = 0; n < 4; n++) {
            int cg = col0 + wc * 64 + n * 16 + cc;
            float bs = bias[cg];
            #pragma unroll
            for (int j = 0; j < 4; j++) {
                float v = acc[m][n][j] + bs;
                size_t off = (size_t)(rg + j) * N + cg;
                if (flags == 1)      ((float*)C)[off] += v;
                else if (flags == 2) ((__hip_bfloat16*)C)[off] = __float2bfloat16(gelu_f(v));
                else if (flags == 3) ((__hip_bfloat16*)C)[off] = __float2bfloat16(v);
                else if (flags == 4) __builtin_nontemporal_store(v, (float*)C + off);
                else                 ((float*)C)[off] = v;
            }
        }
    }
}

// ---------------- small fp32 GEMM (64-row query projections) ----------------
__global__ __launch_bounds__(256) void gemm_k(
    const float* __restrict__ A, const float* __restrict__ W,
    const float* __restrict__ bias, float* __restrict__ C,
    int M, int N, int K)
{
    __shared__ float As[16][68];
    __shared__ float Ws[16][68];
    int tid = threadIdx.x;
    int row0 = blockIdx.y * 64;
    int col0 = blockIdx.x * 64;
    int lr = tid >> 2;
    int lk = (tid & 3) * 4;
    int tx = tid & 15, ty = tid >> 4;
    float acc[4][4] = {};
    const float* Ap = A + (size_t)(row0 + lr) * K + lk;
    const float* Wp = W + (size_t)(col0 + lr) * K + lk;
    for (int k0 = 0; k0 < K; k0 += 16) {
        float4 a4 = *reinterpret_cast<const float4*>(Ap + k0);
        float4 w4 = *reinterpret_cast<const float4*>(Wp + k0);
        As[lk + 0][lr] = a4.x; As[lk + 1][lr] = a4.y; As[lk + 2][lr] = a4.z; As[lk + 3][lr] = a4.w;
        Ws[lk + 0][lr] = w4.x; Ws[lk + 1][lr] = w4.y; Ws[lk + 2][lr] = w4.z; Ws[lk + 3][lr] = w4.w;
        __syncthreads();
        #pragma unroll
        for (int kk = 0; kk < 16; kk++) {
            float4 av = *reinterpret_cast<const float4*>(&As[kk][ty * 4]);
            float4 wv = *reinterpret_cast<const float4*>(&Ws[kk][tx * 4]);
            float avv[4] = {av.x, av.y, av.z, av.w};
            float wvv[4] = {wv.x, wv.y, wv.z, wv.w};
            #pragma unroll
            for (int i = 0; i < 4; i++)
                #pragma unroll
                for (int j = 0; j < 4; j++)
                    acc[i][j] += avv[i] * wvv[j];
        }
        __syncthreads();
    }
    #pragma unroll
    for (int i = 0; i < 4; i++) {
        int r = row0 + ty * 4 + i;
        #pragma unroll
        for (int j = 0; j < 4; j++) {
            int c = col0 + tx * 4 + j;
            C[(size_t)r * N + c] = acc[i][j] + bias[c];
        }
    }
}

// ---------------- layernorm ----------------
template<int OB>
__global__ __launch_bounds__(64) void ln_k(
    const float* __restrict__ in, void* __restrict__ out,
    const float* __restrict__ g, const float* __restrict__ bt,
    int rpb, int in_stride, int in_off, int out_stride, int out_off)
{
    int r = blockIdx.x;
    int b = r / rpb, t = r % rpb;
    const float* xr = in + (size_t)(b * in_stride + in_off + t) * D;
    size_t orow = (size_t)(b * out_stride + out_off + t) * D;
    int lane = threadIdx.x;
    float v[8];
    float s = 0.f;
    #pragma unroll
    for (int i = 0; i < 8; i++) { v[i] = xr[lane + i * 64]; s += v[i]; }
    #pragma unroll
    for (int off = 32; off; off >>= 1) s += __shfl_xor(s, off);
    float mu = s * (1.f / 512.f);
    float vs = 0.f;
    #pragma unroll
    for (int i = 0; i < 8; i++) { float d = v[i] - mu; vs += d * d; }
    #pragma unroll
    for (int off = 32; off; off >>= 1) vs += __shfl_xor(vs, off);
    float rstd = rsqrtf(vs * (1.f / 512.f) + 1e-5f);
    #pragma unroll
    for (int i = 0; i < 8; i++) {
        int c = lane + i * 64;
        float y = (v[i] - mu) * rstd * g[c] + bt[c];
        if (OB) ((__hip_bfloat16*)out)[orow + c] = __float2bfloat16(y);
        else    ((float*)out)[orow + c] = y;
    }
}

// ---------------- fused MFMA causal attention ----------------
__global__ __launch_bounds__(512) void fattn_k(
    const __hip_bfloat16* __restrict__ qkv, __hip_bfloat16* __restrict__ o)
{
    __shared__ __align__(16) __hip_bfloat16 Kl[24 * 512];
    __shared__ __align__(16) __hip_bfloat16 Vl[24 * 512];
    __shared__ __align__(16) __hip_bfloat16 Pl[8 * 512];
    int h = blockIdx.x, b = blockIdx.y;
    int tid = threadIdx.x, w = tid >> 6, l = tid & 63;
    const size_t base = (size_t)b * TTF * 1536 + h * DK;

    for (int it = 0; it < 3; it++) {
        int item = it * 512 + tid;
        int key = item >> 2, dg = item & 3;
        uint4 k4 = *reinterpret_cast<const uint4*>(qkv + base + (size_t)key * 1536 + 512 + dg * 8);
        *reinterpret_cast<uint4*>(&Kl[((key >> 4) * 64 + dg * 16 + (key & 15)) * 8]) = k4;
        uint4 v4 = *reinterpret_cast<const uint4*>(qkv + base + (size_t)key * 1536 + 1024 + dg * 8);
        const ushort* ve = reinterpret_cast<const ushort*>(&v4);
        #pragma unroll
        for (int e = 0; e < 8; e++) {
            int dk = dg * 8 + e;
            int f = (((key & 31) >> 3) << 4) | (dk & 15);
            int idx = (((key >> 5) << 1) + (dk >> 4)) * 512 + f * 8 + (key & 7);
            reinterpret_cast<ushort*>(Vl)[idx] = ve[e];
        }
    }
    __syncthreads();

    const float sc = 0.17677669529663687f;
    __hip_bfloat16* pw = Pl + w * 512;

    for (int iq = 0; iq < 3; iq++) {
        int qt = (iq == 0) ? w : (iq == 1 ? 15 - w : 16 + w);
        int q0 = qt * 16;
        bfrag qf = *reinterpret_cast<const bfrag*>(qkv + base + (size_t)(q0 + (l & 15)) * 1536 + (l >> 4) * 8);
        f32x4 oa0 = (f32x4){0.f, 0.f, 0.f, 0.f};
        f32x4 oa1 = (f32x4){0.f, 0.f, 0.f, 0.f};
        float mrun[4], lrun[4];
        #pragma unroll
        for (int jj = 0; jj < 4; jj++) { mrun[jj] = -3.0e38f; lrun[jj] = 0.f; }
        int ksmax = (q0 + 15) >> 5;

        for (int ks = 0; ks <= ksmax; ks++) {
            bfrag kf0 = *reinterpret_cast<const bfrag*>(&Kl[(ks * 2 + 0) * 512 + l * 8]);
            bfrag kf1 = *reinterpret_cast<const bfrag*>(&Kl[(ks * 2 + 1) * 512 + l * 8]);
            f32x4 z = (f32x4){0.f, 0.f, 0.f, 0.f};
            f32x4 s0 = __builtin_amdgcn_mfma_f32_16x16x32_bf16(qf, kf0, z, 0, 0, 0);
            f32x4 s1 = __builtin_amdgcn_mfma_f32_16x16x32_bf16(qf, kf1, z, 0, 0, 0);
            if (ks == ksmax) {
                #pragma unroll
                for (int jj = 0; jj < 4; jj++) {
                    int q = q0 + ((l >> 4) << 2) + jj;
                    if (ks * 32 + (l & 15) > q)      s0[jj] = -3.0e38f;
                    if (ks * 32 + 16 + (l & 15) > q) s1[jj] = -3.0e38f;
                }
            }
            float p0[4], p1[4], ps[4];
            #pragma unroll
            for (int jj = 0; jj < 4; jj++) {
                float sm = fmaxf(s0[jj], s1[jj]);
                #pragma unroll
                for (int off = 1; off <= 8; off <<= 1) sm = fmaxf(sm, __shfl_xor(sm, off));
                float mnew = fmaxf(mrun[jj], sm);
                float f = __expf((mrun[jj] - mnew) * sc);
                mrun[jj] = mnew;
                lrun[jj] *= f;
                oa0[jj] *= f; oa1[jj] *= f;
                p0[jj] = __expf((s0[jj] - mnew) * sc);
                p1[jj] = __expf((s1[jj] - mnew) * sc);
                ps[jj] = p0[jj] + p1[jj];
            }
            #pragma unroll
            for (int jj = 0; jj < 4; jj++) {
                float t = ps[jj];
                #pragma unroll
                for (int off = 1; off <= 8; off <<= 1) t += __shfl_xor(t, off);
                lrun[jj] += t;
            }
            #pragma unroll
            for (int jj = 0; jj < 4; jj++) {
                int ql = ((l >> 4) << 2) + jj;
                int kl0 = l & 15, kl1 = 16 + (l & 15);
                pw[((kl0 >> 3) * 16 + ql) * 8 + (kl0 & 7)] = __float2bfloat16(p0[jj]);
                pw[((kl1 >> 3) * 16 + ql) * 8 + (kl1 & 7)] = __float2bfloat16(p1[jj]);
            }
            bfrag pf  = *reinterpret_cast<const bfrag*>(&pw[l * 8]);
            bfrag vf0 = *reinterpret_cast<const bfrag*>(&Vl[(ks * 2 + 0) * 512 + l * 8]);
            bfrag vf1 = *reinterpret_cast<const bfrag*>(&Vl[(ks * 2 + 1) * 512 + l * 8]);
            oa0 = __builtin_amdgcn_mfma_f32_16x16x32_bf16(pf, vf0, oa0, 0, 0, 0);
            oa1 = __builtin_amdgcn_mfma_f32_16x16x32_bf16(pf, vf1, oa1, 0, 0, 0);
        }
        #pragma unroll
        for (int jj = 0; jj < 4; jj++) {
            float inv = 1.0f / lrun[jj];
            int q = q0 + ((l >> 4) << 2) + jj;
            size_t orow = ((size_t)b * TTF + q) * D + h * DK;
            o[orow + (l & 15)]      = __float2bfloat16(oa0[jj] * inv);
            o[orow + 16 + (l & 15)] = __float2bfloat16(oa1[jj] * inv);
        }
    }
}

// ---------------- summarizer attention ----------------
template<int NI>
__global__ __launch_bounds__(64) void attn_sum_k(
    const float* __restrict__ q, const float* __restrict__ kv,
    __hip_bfloat16* __restrict__ o, int tlen)
{
    int qi = blockIdx.x, h = blockIdx.y, b = blockIdx.z;
    int lane = threadIdx.x;
    __shared__ float qs[DK];
    if (lane < DK) qs[lane] = q[(size_t)qi * D + h * DK + lane];
    __syncthreads();
    float sc[NI];
    float m = -1e30f;
    #pragma unroll
    for (int i = 0; i < NI; i++) {
        sc[i] = 0.f;
        int t = lane + i * 64;
        if (t < tlen) {
            const float* kr = kv + (size_t)(b * tlen + t) * 1024 + h * DK;
            float d = 0.f;
            #pragma unroll
            for (int dk = 0; dk < DK; dk++) d += qs[dk] * kr[dk];
            d *= 0.17677669529663687f;
            sc[i] = d;
            m = fmaxf(m, d);
        }
    }
    #pragma unroll
    for (int off = 32; off; off >>= 1) m = fmaxf(m, __shfl_xor(m, off));
    float sum = 0.f;
    #pragma unroll
    for (int i = 0; i < NI; i++) {
        int t = lane + i * 64;
        if (t < tlen) { sc[i] = expf(sc[i] - m); sum += sc[i]; }
    }
    #pragma unroll
    for (int off = 32; off; off >>= 1) sum += __shfl_xor(sum, off);
    float inv = 1.f / sum;
    float oa[DK];
    #pragma unroll
    for (int dk = 0; dk < DK; dk++) oa[dk] = 0.f;
    #pragma unroll
    for (int i = 0; i < NI; i++) {
        int t = lane + i * 64;
        if (t < tlen) {
            const float* vr = kv + (size_t)(b * tlen + t) * 1024 + 512 + h * DK;
            float a = sc[i] * inv;
            #pragma unroll
            for (int dk = 0; dk < DK; dk++) oa[dk] += a * vr[dk];
        }
    }
    #pragma unroll
    for (int dk = 0; dk < DK; dk++) {
        float vv = oa[dk];
        #pragma unroll
        for (int off = 32; off; off >>= 1) vv += __shfl_xor(vv, off);
        if (lane == 0) o[(size_t)(b * 64 + qi) * D + h * DK + dk] = __float2bfloat16(vv);
    }
}

// ---------------- tgt copy ----------------
__global__ __launch_bounds__(256) void tgt_k(const int* __restrict__ tids, float* __restrict__ out)
{
    int i = blockIdx.x * 256 + threadIdx.x;
    int b = i >> 8, c = i & 255;
    out[i] = (float)tids[b * 1024 + 768 + c];
}

extern "C" void kernel_launch(void* const* d_in, const int* in_sizes, int n_in,
                              void* d_out, int out_size, void* d_ws, size_t ws_size,
                              hipStream_t stream) {
    (void)in_sizes; (void)n_in; (void)out_size; (void)ws_size;
    const int*   input_ids  = (const int*)  d_in[0];
    const int*   target_ids = (const int*)  d_in[1];
    const float* emb_sem    = (const float*)d_in[2];
    const float* emb_pos    = (const float*)d_in[3];
    const float* lg_sem     = (const float*)d_in[4];
    const float* lg_pos     = (const float*)d_in[5];
    const float* lg_inw     = (const float*)d_in[6];
    const float* lg_inb     = (const float*)d_in[7];
    const float* lg_outw    = (const float*)d_in[8];
    const float* lg_outb    = (const float*)d_in[9];
    const float* lg_tok     = (const float*)d_in[10];
    const float* lg_lng     = (const float*)d_in[11];
    const float* lg_lnb     = (const float*)d_in[12];
    const float* md_sem     = (const float*)d_in[13];
    const float* md_pos     = (const float*)d_in[14];
    const float* md_inw     = (const float*)d_in[15];
    const float* md_inb     = (const float*)d_in[16];
    const float* md_outw    = (const float*)d_in[17];
    const float* md_outb    = (const float*)d_in[18];
    const float* md_tok     = (const float*)d_in[19];
    const float* md_lng     = (const float*)d_in[20];
    const float* md_lnb     = (const float*)d_in[21];
    const float* qkv_w      = (const float*)d_in[22];
    const float* qkv_b      = (const float*)d_in[23];
    const float* wo_w       = (const float*)d_in[24];
    const float* wo_b       = (const float*)d_in[25];
    const float* ln1_g      = (const float*)d_in[26];
    const float* ln1_b      = (const float*)d_in[27];
    const float* ln2_g      = (const float*)d_in[28];
    const float* ln2_b      = (const float*)d_in[29];
    const float* ff1_w      = (const float*)d_in[30];
    const float* ff1_b      = (const float*)d_in[31];
    const float* ff2_w      = (const float*)d_in[32];
    const float* ff2_b      = (const float*)d_in[33];
    const float* hd_lng     = (const float*)d_in[34];
    const float* hd_lnb     = (const float*)d_in[35];
    const float* hd_w       = (const float*)d_in[36];
    const float* hd_b       = (const float*)d_in[37];

    // ---- workspace layout ----
    float* x    = (float*)d_ws;              // 3,145,728 f32
    float* qkvb = x    + 3145728;            // 9,437,184 f32 (summarizer KV; layers reuse as bf16 qkv)
    float* so2  = qkvb + 9437184;            // 524,288 f32
    float* q_s  = so2  + 524288;             // 32,768 f32
    __hip_bfloat16* qkv_bf = (__hip_bfloat16*)qkvb;
    __hip_bfloat16* h_bf   = (__hip_bfloat16*)(q_s + 32768);   // 3,145,728 bf16
    __hip_bfloat16* a_bf   = h_bf   + 3145728;                 // 6,291,456 bf16
    __hip_bfloat16* sumo_bf= a_bf   + 6291456;                 // 524,288 bf16
    __hip_bfloat16* w_qkv  = sumo_bf+ 524288;                  // 12,582,912
    __hip_bfloat16* w_wo   = w_qkv  + 12582912;                // 4,194,304
    __hip_bfloat16* w_ff1  = w_wo   + 4194304;                 // 8,388,608
    __hip_bfloat16* w_ff2  = w_ff1  + 8388608;                 // 8,388,608
    __hip_bfloat16* w_hd   = w_ff2  + 8388608;                 // 16,777,216
    __hip_bfloat16* w_lgin = w_hd   + 16777216;                // 786,432
    __hip_bfloat16* w_mdin = w_lgin + 786432;                  // 786,432
    __hip_bfloat16* w_lgout= w_mdin + 786432;                  // 262,144
    __hip_bfloat16* w_mdout= w_lgout+ 262144;                  // 262,144

    // ---- weight conversion ----
    cvt_k<<<12582912 / 2048, 256, 0, stream>>>(qkv_w, w_qkv, 12582912);
    cvt_k<<< 4194304 / 2048, 256, 0, stream>>>(wo_w,  w_wo,   4194304);
    cvt_k<<< 8388608 / 2048, 256, 0, stream>>>(ff1_w, w_ff1,  8388608);
    cvt_k<<< 8388608 / 2048, 256, 0, stream>>>(ff2_w, w_ff2,  8388608);
    cvt_k<<<16777216 / 2048, 256, 0, stream>>>(hd_w,  w_hd,  16777216);
    cvt_k<<<  786432 / 2048, 256, 0, stream>>>(lg_inw, w_lgin, 786432);
    cvt_k<<<  786432 / 2048, 256, 0, stream>>>(md_inw, w_mdin, 786432);
    cvt_k<<<  262144 / 2048, 256, 0, stream>>>(lg_outw, w_lgout, 262144);
    cvt_k<<<  262144 / 2048, 256, 0, stream>>>(md_outw, w_mdout, 262144);

    // ======== summarizer LG (tlen=512) ========
    embed_k<1><<<dim3(512, NB), 128, 0, stream>>>(input_ids, 1024, 0, lg_sem, lg_pos, a_bf, 512, 0);
    mgemm_k<<<dim3(8, 64), 256, 0, stream>>>(a_bf, w_lgin + 512 * 512, lg_inb + 512, qkvb, 8192, 1024, 512, 0);
    gemm_k<<<dim3(8, 1), 256, 0, stream>>>(lg_tok, lg_inw, lg_inb, q_s, 64, 512, 512);
    attn_sum_k<8><<<dim3(64, NHEAD, NB), 64, 0, stream>>>(q_s, qkvb, sumo_bf, 512);
    mgemm_k<<<dim3(4, 8), 256, 0, stream>>>(sumo_bf, w_lgout, lg_outb, so2, 1024, 512, 512, 0);
    ln_k<0><<<1024, 64, 0, stream>>>(so2, x, lg_lng, lg_lnb, 64, 64, 0, TTF, 0);

    // ======== summarizer MD (tlen=256) ========
    embed_k<1><<<dim3(256, NB), 128, 0, stream>>>(input_ids, 1024, 512, md_sem, md_pos, a_bf, 256, 0);
    mgemm_k<<<dim3(8, 32), 256, 0, stream>>>(a_bf, w_mdin + 512 * 512, md_inb + 512, qkvb, 4096, 1024, 512, 0);
    gemm_k<<<dim3(8, 1), 256, 0, stream>>>(md_tok, md_inw, md_inb, q_s, 64, 512, 512);
    attn_sum_k<4><<<dim3(64, NHEAD, NB), 64, 0, stream>>>(q_s, qkvb, sumo_bf, 256);
    mgemm_k<<<dim3(4, 8), 256, 0, stream>>>(sumo_bf, w_mdout, md_outb, so2, 1024, 512, 512, 0);
    ln_k<0><<<1024, 64, 0, stream>>>(so2, x, md_lng, md_lnb, 64, 64, 0, TTF, 64);

    // ======== core embeddings into x[:, 128:384, :] ========
    embed_k<0><<<dim3(256, NB), 128, 0, stream>>>(input_ids, 1024, 768, emb_sem, emb_pos, x, TTF, 128);

    // ======== 16 transformer layers ========
    for (int l = 0; l < NLAYER; l++) {
        ln_k<1><<<6144, 64, 0, stream>>>(x, h_bf, ln1_g + l * D, ln1_b + l * D, TTF, TTF, 0, TTF, 0);
        mgemm_k<<<dim3(12, 48), 256, 0, stream>>>(h_bf, w_qkv + (size_t)l * 1536 * 512, qkv_b + l * 1536, qkv_bf, 6144, 1536, 512, 3);
        fattn_k<<<dim3(NHEAD, NB), 512, 0, stream>>>(qkv_bf, a_bf);
        mgemm_k<<<dim3(4, 48), 256, 0, stream>>>(a_bf, w_wo + (size_t)l * 512 * 512, wo_b + l * D, x, 6144, 512, 512, 1);
        ln_k<1><<<6144, 64, 0, stream>>>(x, h_bf, ln2_g + l * D, ln2_b + l * D, TTF, TTF, 0, TTF, 0);
        mgemm_k<<<dim3(8, 48), 256, 0, stream>>>(h_bf, w_ff1 + (size_t)l * 1024 * 512, ff1_b + l * FF, a_bf, 6144, 1024, 512, 2);
        mgemm_k<<<dim3(4, 48), 256, 0, stream>>>(a_bf, w_ff2 + (size_t)l * 512 * 1024, ff2_b + l * D, x, 6144, 512, 1024, 1);
    }

    // ======== head ========
    ln_k<1><<<4096, 64, 0, stream>>>(x, h_bf, hd_lng, hd_lnb, NCORE, TTF, 128, NCORE, 0);
    float* logits = (float*)d_out;
    mgemm_k<<<dim3(256, 32), 256, 0, stream>>>(h_bf, w_hd, hd_b, logits, 4096, VOC, 512, 4);
    tgt_k<<<16, 256, 0, stream>>>(target_ids, logits + (size_t)NB * NCORE * VOC);
}